// Round 2
// baseline (936.018 us; speedup 1.0000x reference)
//
#include <hip/hip_runtime.h>
#include <hip/hip_bf16.h>
#include <hip/hip_cooperative_groups.h>

namespace cg = cooperative_groups;

#define B_N 16
#define U_N 2048
#define S_N 512
#define D_N 128
#define INV_SQRT_D 0.08838834764831845f

typedef unsigned long long ull;
typedef __attribute__((ext_vector_type(8))) short bf16x8;
typedef __attribute__((ext_vector_type(4))) float f32x4;
typedef __attribute__((ext_vector_type(4))) _Float16 f16x4;

// ---------- helpers ----------
__device__ __forceinline__ unsigned monof(float v) {
    unsigned b = __float_as_uint(v);
    return (b & 0x80000000u) ? ~b : (b | 0x80000000u);
}
__device__ __forceinline__ float unmonof(unsigned m) {
    unsigned b = (m & 0x80000000u) ? (m & 0x7fffffffu) : ~m;
    return __uint_as_float(b);
}
__device__ __forceinline__ unsigned short f2bf(float x) {  // RNE fp32->bf16
    unsigned u = __float_as_uint(x);
    return (unsigned short)((u + 0x7fffu + ((u >> 16) & 1u)) >> 16);
}

// ---------- init: zero state, pack needs/caps/fd masks ----------
__global__ void init_state(const float* __restrict__ servers, const float* __restrict__ users,
                           const int* __restrict__ fd_onehot,
                           unsigned* allocU, uint4* alloc3, unsigned* rcArr, unsigned* seenArr,
                           float* logp, float* capA, float* invA, unsigned* fdm, float* nds,
                           unsigned* any_valid) {
    int i = blockIdx.x * 256 + threadIdx.x;  // 2048 blocks -> 524288 threads
    if (i < B_N * U_N * 16) allocU[i] = 0u;
    if (i < B_N * U_N) {
        rcArr[i] = 0u; seenArr[i] = 0u; logp[i] = 0.f;
        alloc3[i] = make_uint4(0xFFFFFFFFu, 0xFFFFFFFFu, 0xFFFFFFFFu, 0xFFFFFFFFu);
        const float* up = users + (size_t)i * 6;
        nds[i * 4 + 0] = up[2]; nds[i * 4 + 1] = up[3];
        nds[i * 4 + 2] = up[4]; nds[i * 4 + 3] = up[5];
    }
    if (i < B_N * S_N) {
        const float* sp = servers + (size_t)i * 7;
        float4 c = make_float4(sp[3], sp[4], sp[5], sp[6]);
        ((float4*)capA)[i] = c;
        ((float4*)invA)[i] = make_float4(1.f / fmaxf(c.x, 1e-6f), 1.f / fmaxf(c.y, 1e-6f),
                                         1.f / fmaxf(c.z, 1e-6f), 1.f / fmaxf(c.w, 1e-6f));
        unsigned w = 0u;
        const int* fp = fd_onehot + (size_t)i * 32;
        #pragma unroll
        for (int f = 0; f < 32; ++f) w |= (fp[f] != 0 ? 1u : 0u) << f;
        fdm[i] = w;
    }
    if (i < 16) any_valid[i] = 0u;
}

// ---------- pack connect (B,U,S) int32 -> (B,U,S-bits): ballot per wave ----------
__global__ void pack_connect(const int* __restrict__ connect, ull* __restrict__ connU) {
    int i = blockIdx.x * 4 + (threadIdx.x >> 6);  // row index in [0, B*U)
    int lane = threadIdx.x & 63;
    const int* row = connect + (size_t)i * S_N;
    #pragma unroll
    for (int c = 0; c < 8; ++c) {
        ull m = __ballot(row[c * 64 + lane] != 0);
        if (lane == 0) connU[(size_t)i * 8 + c] = m;
    }
}

// ---------- generic fp32 GEMM: C[z][m][n] = scale * sum_k (A[z][m][k](+abias[k])) * B[n][k]
// OUTMODE: 0 = fp32 only, 1 = bf16 only, 2 = both
template <bool ABIAS, int OUTMODE>
__global__ __launch_bounds__(256) void gemm_nt(const float* __restrict__ A, const float* __restrict__ Bm,
                                               const float* __restrict__ abias, float* __restrict__ C,
                                               unsigned short* __restrict__ C16,
                                               int M, int N, int K, float scale) {
    __shared__ float As[16][68];
    __shared__ float Bs[16][68];
    int z = blockIdx.z;
    const float* Ab = A + (size_t)z * M * K;
    const float* Bb = Bm;
    int m0 = blockIdx.x * 64, n0 = blockIdx.y * 64;
    int tid = threadIdx.x;
    int tx = tid & 15, ty = tid >> 4;
    int lrow = tid >> 2, lk = (tid & 3) * 4;
    float acc[4][4] = {};
    for (int k0 = 0; k0 < K; k0 += 16) {
        float4 av = *(const float4*)(Ab + (size_t)(m0 + lrow) * K + k0 + lk);
        float4 bv = *(const float4*)(Bb + (size_t)(n0 + lrow) * K + k0 + lk);
        if (ABIAS) {
            av.x += abias[k0 + lk]; av.y += abias[k0 + lk + 1];
            av.z += abias[k0 + lk + 2]; av.w += abias[k0 + lk + 3];
        }
        __syncthreads();
        As[lk + 0][lrow] = av.x; As[lk + 1][lrow] = av.y; As[lk + 2][lrow] = av.z; As[lk + 3][lrow] = av.w;
        Bs[lk + 0][lrow] = bv.x; Bs[lk + 1][lrow] = bv.y; Bs[lk + 2][lrow] = bv.z; Bs[lk + 3][lrow] = bv.w;
        __syncthreads();
        #pragma unroll
        for (int kk = 0; kk < 16; ++kk) {
            float4 a = *(const float4*)&As[kk][ty * 4];
            float4 bq = *(const float4*)&Bs[kk][tx * 4];
            float ar[4] = {a.x, a.y, a.z, a.w}, br[4] = {bq.x, bq.y, bq.z, bq.w};
            #pragma unroll
            for (int ii = 0; ii < 4; ++ii)
                #pragma unroll
                for (int jj = 0; jj < 4; ++jj) acc[ii][jj] += ar[ii] * br[jj];
        }
    }
    #pragma unroll
    for (int ii = 0; ii < 4; ++ii) {
        float4 o = make_float4(acc[ii][0] * scale, acc[ii][1] * scale,
                               acc[ii][2] * scale, acc[ii][3] * scale);
        size_t idx = (size_t)z * M * N + (size_t)(m0 + ty * 4 + ii) * N + n0 + tx * 4;
        if (OUTMODE != 1) *(float4*)(C + idx) = o;
        if (OUTMODE != 0) {
            ushort4 ob;
            ob.x = f2bf(o.x); ob.y = f2bf(o.y); ob.z = f2bf(o.z); ob.w = f2bf(o.w);
            *(ushort4*)(C16 + idx) = ob;
        }
    }
}

// ---------- M3[e][c] = sum_d ptr_q_w[d,e] * (inv_sqrt_d * sum_f ptr_k_w[d,f]*state_proj_w[f,c]) ----
__global__ void m3_kernel(const float* __restrict__ kw, const float* __restrict__ spw,
                          const float* __restrict__ qw, float* __restrict__ M3) {
    __shared__ float M2s[512];
    int t = threadIdx.x;
    {
        int d = t >> 2, c = t & 3;
        float acc = 0.f;
        for (int e = 0; e < 128; ++e) acc += kw[d * 128 + e] * spw[e * 4 + c];
        M2s[d * 4 + c] = acc * INV_SQRT_D;
    }
    __syncthreads();
    {
        int e = t >> 2, c = t & 3;
        float acc = 0.f;
        for (int d = 0; d < 128; ++d) acc += qw[d * 128 + e] * M2s[d * 4 + c];
        M3[e * 4 + c] = acc;
    }
}

// ---------- qm[b,u,c] = sum_e user_enc[b,u,e]*M3[e,c] ----------
__global__ void qm_kernel(const float* __restrict__ enc, const float* __restrict__ M3, float* __restrict__ qm) {
    __shared__ float qs[64][129];
    __shared__ float m3s[512];
    int b = blockIdx.y, u0 = blockIdx.x * 64;
    int t = threadIdx.x;
    for (int i = t; i < 512; i += 256) m3s[i] = M3[i];
    #pragma unroll
    for (int it = 0; it < 8; ++it) {
        int f4 = t + 256 * it;
        int row = f4 >> 5;
        int col = (f4 & 31) * 4;
        float4 v = *(const float4*)(enc + ((size_t)(b * U_N + u0 + row)) * D_N + col);
        qs[row][col] = v.x; qs[row][col + 1] = v.y; qs[row][col + 2] = v.z; qs[row][col + 3] = v.w;
    }
    __syncthreads();
    int ul = t >> 2, c = t & 3;
    float acc = 0.f;
    for (int d = 0; d < 128; ++d) acc += qs[ul][d] * m3s[d * 4 + c];
    qm[((size_t)(b * U_N + u0 + ul)) * 4 + c] = acc;
}

// ---------- qk MFMA: qkh[b][u][s] = fp16( sum_k qb[b][u][k]*kb[b][s][k] ), bf16 inputs. ----------
__global__ __launch_bounds__(256) void qk_mfma(const unsigned short* __restrict__ qb,
                                               const unsigned short* __restrict__ kb,
                                               _Float16* __restrict__ qkh) {
    const int b = blockIdx.z, u0 = blockIdx.x * 128, s0 = blockIdx.y * 64;
    const int t = threadIdx.x, w = t >> 6, l = t & 63;
    const int lr = l & 15, lq = l >> 4;
    const unsigned short* Ab = qb + ((size_t)(b * U_N + u0 + w * 32 + lr)) * D_N + lq * 8;
    const unsigned short* Bb = kb + ((size_t)(b * S_N + s0 + lr)) * D_N + lq * 8;
    f32x4 acc[2][4] = {};
    #pragma unroll
    for (int kt = 0; kt < 4; ++kt) {
        bf16x8 a0 = *(const bf16x8*)(Ab + kt * 32);
        bf16x8 a1 = *(const bf16x8*)(Ab + 16 * D_N + kt * 32);
        #pragma unroll
        for (int c = 0; c < 4; ++c) {
            bf16x8 bf = *(const bf16x8*)(Bb + c * 16 * D_N + kt * 32);
            acc[0][c] = __builtin_amdgcn_mfma_f32_16x16x32_bf16(a0, bf, acc[0][c], 0, 0, 0);
            acc[1][c] = __builtin_amdgcn_mfma_f32_16x16x32_bf16(a1, bf, acc[1][c], 0, 0, 0);
        }
    }
    __shared__ _Float16 Cs[128][72];
    #pragma unroll
    for (int mt = 0; mt < 2; ++mt)
        #pragma unroll
        for (int c = 0; c < 4; ++c)
            #pragma unroll
            for (int r = 0; r < 4; ++r)
                Cs[w * 32 + mt * 16 + lq * 4 + r][c * 16 + lr] = (_Float16)acc[mt][c][r];
    __syncthreads();
    #pragma unroll
    for (int k = 0; k < 4; ++k) {
        int row = (t >> 3) + k * 32;
        int sg = (t & 7) * 8;
        uint4 v = *(const uint4*)&Cs[row][sg];
        *(uint4*)(qkh + ((size_t)(b * U_N + u0 + row)) * S_N + s0 + sg) = v;
    }
}

// =====================================================================================
// Cooperative fused iteration loop: 256 blocks x 1024 threads = 1 block/CU.
// Per iter: score phase (all blocks) -> grid.sync -> apply phase (16 blocks) -> grid.sync.
// Finalize (logp/alloc/cap) folded at the end. LDS: 48KB unioned across phases.
// =====================================================================================
__global__ __launch_bounds__(1024) void alloc_loop(
    const _Float16* __restrict__ qkh, const float* __restrict__ qm4,
    const float* __restrict__ nds, const unsigned* __restrict__ connU32,
    uint4* __restrict__ alloc3, unsigned* __restrict__ allocU,
    unsigned* __restrict__ rcArr, unsigned* __restrict__ seenArr,
    const unsigned* __restrict__ fdm_,
    float* __restrict__ capA, const float* __restrict__ invA,
    const float* __restrict__ usw, const float* __restrict__ sbp,
    const float* __restrict__ fdbp,
    ull* __restrict__ keypart, float* __restrict__ sumpart,
    float* __restrict__ logp, unsigned* __restrict__ any_valid,
    float* __restrict__ out) {
    cg::grid_group grid = cg::this_grid();
    __shared__ __align__(16) char smem[49152];
    // score overlay
    ull (*mk)[128][4] = (ull (*)[128][4])smem;              // 32768 B
    float (*me)[128][4] = (float (*)[128][4])(smem + 32768); // 16384 B
    // apply overlay
    ull* ukeyL = (ull*)smem;                                 // 16384 B
    unsigned* sgL = (unsigned*)(smem + 16384);               //  8192 B
    ull* bkL = (ull*)(smem + 24576);                         //  4096 B
    float* bsL = (float*)(smem + 28672);                     //  2048 B
    float* lpL = (float*)(smem + 30720);                     //  2048 B

    const int tid = threadIdx.x;
    const int b = blockIdx.x & 15;        // b fastest -> batches spread across XCDs
    const int ublk = blockIdx.x >> 4;     // 0..15, 128 users each
    const int u0 = ublk << 7;
    const int h = tid >> 7;               // user octant (16 users each)
    const int sl = tid & 127;             // server quad: servers 4sl..4sl+3
    const int s0 = sl * 4;
    const float w0 = usw[0], w1 = usw[1], w2 = usw[2], sb = sbp[0], fdb = fdbp[0];
    const float ub0 = sb + w1;
    const float ub1 = sb + w0 * (1.f / 3.f) + w1 * (2.f / 3.f);
    const float ub2 = sb + w0 * (2.f / 3.f) + w1 * (1.f / 3.f) + w2;
    const int bsb = b * S_N + s0;
    const int gub = b * U_N + u0 + h * 16;
    const _Float16* qkbase = qkh + (size_t)gub * S_N + s0;
    const int cwbase = gub * 16 + (sl >> 3);
    const int nsh = (sl & 7) * 4;
    // iteration-invariant per-thread state (hoisted: was reloaded every launch before)
    float4 iv[4]; unsigned fq[4];
    #pragma unroll
    for (int j = 0; j < 4; ++j) {
        iv[j] = ((const float4*)invA)[bsb + j];
        fq[j] = fdm_[bsb + j];
    }
    ull connbits = 0ULL;  // 16 users x 4 servers connect bits packed in one reg
    #pragma unroll
    for (int uu = 0; uu < 16; ++uu)
        connbits |= (ull)((connU32[cwbase + uu * 16] >> nsh) & 0xFu) << (4 * uu);

    for (int iter = 0; iter < 16; ++iter) {
        // ===================== score phase (all 256 blocks) =====================
        float4 cap[4], cr[4];
        #pragma unroll
        for (int j = 0; j < 4; ++j) {
            cap[j] = ((const float4*)capA)[bsb + j];
            cr[j] = make_float4(cap[j].x * iv[j].x, cap[j].y * iv[j].y,
                                cap[j].z * iv[j].z, cap[j].w * iv[j].w);
        }
        ull k[4] = {0ULL, 0ULL, 0ULL, 0ULL};
        float e[4] = {0.f, 0.f, 0.f, 0.f};
        #pragma unroll 2
        for (int uu = 0; uu < 16; ++uu) {
            const int gu = gub + uu;
            const unsigned rcu = rcArr[gu];            // wave-uniform scalar load
            if (rcu < 3u) {                             // uniform skip: saturated users free
                const f16x4 qv = *(const f16x4*)(qkbase + (size_t)uu * S_N);
                const float4 qmv = ((const float4*)qm4)[gu];
                const float4 ndv = ((const float4*)nds)[gu];
                const unsigned snu = seenArr[gu];
                const uint4 al = alloc3[gu];
                const unsigned nib = (unsigned)(connbits >> (4 * uu)) & 0xFu;
                const float add = (rcu == 0u) ? ub0 : ((rcu == 1u) ? ub1 : ub2);
                const unsigned uinv = ~(unsigned)(u0 + h * 16 + uu);
                #pragma unroll
                for (int j = 0; j < 4; ++j) {
                    const unsigned us = (unsigned)(s0 + j);
                    const bool ful = (cap[j].x >= ndv.x) & (cap[j].y >= ndv.y) &
                                     (cap[j].z >= ndv.z) & (cap[j].w >= ndv.w);
                    const bool aok = (al.x != us) & (al.y != us) & (al.z != us);
                    const bool el = (((nib >> j) & 1u) != 0u) & ful & aok;
                    const float lg = (float)qv[j] + qmv.x * cr[j].x + qmv.y * cr[j].y +
                                     qmv.z * cr[j].z + qmv.w * cr[j].w + add +
                                     (((snu & fq[j]) == 0u) ? fdb : 0.f);
                    if (el) {
                        const ull kk = ((ull)monof(lg) << 32) | uinv;
                        k[j] = k[j] > kk ? k[j] : kk;
                        e[j] += __expf(lg);
                    }
                }
            }
        }
        #pragma unroll
        for (int j = 0; j < 4; ++j) { mk[h][sl][j] = k[j]; me[h][sl][j] = e[j]; }
        __syncthreads();
        if (tid < 512) {
            const int sl2 = tid >> 2, j2 = tid & 3;
            ull kb2 = mk[0][sl2][j2];
            float eb = me[0][sl2][j2];
            #pragma unroll
            for (int o = 1; o < 8; ++o) {
                const ull kk = mk[o][sl2][j2];
                kb2 = kk > kb2 ? kk : kb2;
                eb += me[o][sl2][j2];
            }
            const size_t p = (size_t)ublk * (B_N * S_N) + (size_t)b * S_N + sl2 * 4 + j2;
            keypart[p] = kb2;
            sumpart[p] = eb;
        }
        grid.sync();
        // ===================== apply phase (16 blocks, ublk==0) =====================
        if (ublk == 0) {
            ukeyL[tid] = 0ULL; ukeyL[tid + 1024] = 0ULL;
            sgL[tid] = 0u; sgL[tid + 1024] = 0u;
            __syncthreads();
            const int s = tid & 511, hh = tid >> 9;
            const int base = b * S_N + s;
            ull best = 0ULL; float ssum = 0.f;
            #pragma unroll
            for (int j = hh * 8; j < hh * 8 + 8; ++j) {
                const ull kk = keypart[(size_t)j * (B_N * S_N) + base];
                best = kk > best ? kk : best;
                ssum += sumpart[(size_t)j * (B_N * S_N) + base];
            }
            if (hh == 0) { bkL[s] = best; bsL[s] = ssum; }
            __syncthreads();
            unsigned prop = 0u;
            if (hh == 1) {
                const ull ob = bkL[s];
                best = ob > best ? ob : best;
                ssum += bsL[s];
                if (best != 0ULL) {
                    const float mx = unmonof((unsigned)(best >> 32));
                    const unsigned pu = ~(unsigned)best;   // winning user (ties -> smallest u)
                    lpL[s] = mx - __logf(ssum);            // max - logsumexp
                    const ull pk = ((ull)monof(mx) << 32) | (~(unsigned)s);
                    atomicMax(&ukeyL[pu], pk);
                    atomicOr(&sgL[pu], fdm_[base]);
                    prop = 1u;
                }
            }
            const ull bal = __ballot(prop != 0u);
            if (bal != 0ULL && (tid & 63) == 0) atomicOr(&any_valid[iter], 1u);
            __syncthreads();
            #pragma unroll
            for (int g = 0; g < 2; ++g) {
                const int u = tid + g * 1024;
                const ull key = ukeyL[u];
                if (key != 0ULL) {                         // user received >=1 proposal
                    const int gu = b * U_N + u;
                    const unsigned s2 = ~(unsigned)key;    // accepted server
                    const int bs2 = b * S_N + (int)s2;
                    uint4 al = alloc3[gu];
                    const unsigned r = rcArr[gu];
                    if (r == 0u) al.x = s2; else if (r == 1u) al.y = s2; else al.z = s2;
                    alloc3[gu] = al;
                    allocU[gu * 16 + (s2 >> 5)] |= 1u << (s2 & 31u);
                    const float4 nd = ((const float4*)nds)[gu];
                    float4 cv = ((float4*)capA)[bs2];
                    cv.x = fmaxf(cv.x - nd.x, 0.f); cv.y = fmaxf(cv.y - nd.y, 0.f);
                    cv.z = fmaxf(cv.z - nd.z, 0.f); cv.w = fmaxf(cv.w - nd.w, 0.f);
                    ((float4*)capA)[bs2] = cv;
                    rcArr[gu] = r + 1u;
                    logp[gu] += lpL[s2];
                    seenArr[gu] |= sgL[u];
                }
            }
        }
        grid.sync();
        if (__hip_atomic_load(any_valid + iter, __ATOMIC_RELAXED,
                              __HIP_MEMORY_SCOPE_AGENT) == 0u) break;  // frozen chain
    }
    // ===================== finalize (folded) =====================
    if (ublk == 0) {  // logp sum for batch b
        float s = 0.f;
        for (int u = tid; u < U_N; u += 1024) s += logp[b * U_N + u];
        #pragma unroll
        for (int m = 1; m < 64; m <<= 1) s += __shfl_xor(s, m, 64);
        float* rr = (float*)smem;
        if ((tid & 63) == 0) rr[tid >> 6] = s;
        __syncthreads();
        if (tid == 0) {
            float tt = 0.f;
            #pragma unroll
            for (int i2 = 0; i2 < 16; ++i2) tt += rr[i2];
            out[b] = tt;
        }
    }
    if (ublk == 1) {  // cap tail for batch b
        for (int i2 = tid; i2 < S_N * 4; i2 += 1024)
            out[16 + (size_t)B_N * U_N * S_N + b * S_N * 4 + i2] = capA[b * S_N * 4 + i2];
    }
    {   // alloc one-hot: each block writes its own (b, 128-user) slice
        const int rowbase = b * U_N + u0;
        for (int i2 = tid; i2 < 128 * 128; i2 += 1024) {
            const int row = i2 >> 7, s4 = (i2 & 127) * 4;
            const unsigned wv = allocU[(rowbase + row) * 16 + (s4 >> 5)];
            float4 o;
            o.x = ((wv >> ((s4 + 0) & 31)) & 1u) ? 1.f : 0.f;
            o.y = ((wv >> ((s4 + 1) & 31)) & 1u) ? 1.f : 0.f;
            o.z = ((wv >> ((s4 + 2) & 31)) & 1u) ? 1.f : 0.f;
            o.w = ((wv >> ((s4 + 3) & 31)) & 1u) ? 1.f : 0.f;
            *(float4*)(out + 16 + (size_t)(rowbase + row) * S_N + s4) = o;
        }
    }
}

// =====================================================================================
// Fallback path (used only if cooperative launch is unavailable): previous-round kernels
// =====================================================================================
__global__ __launch_bounds__(1024, 1) void iter_score(
    const _Float16* __restrict__ qkh, const float* __restrict__ qm4,
    const float* __restrict__ nds, const unsigned* __restrict__ connU32,
    const uint4* __restrict__ alloc3, const unsigned* __restrict__ rcArr,
    const unsigned* __restrict__ seenArr, const unsigned* __restrict__ fdm_,
    const float* __restrict__ capA, const float* __restrict__ invA,
    const float* __restrict__ usw, const float* __restrict__ sbp, const float* __restrict__ fdbp,
    ull* __restrict__ keypart, float* __restrict__ sumpart,
    const unsigned* __restrict__ any_valid, int iter) {
    if (iter > 0 && any_valid[iter - 1] == 0u) return;
    const int tid = threadIdx.x;
    const int b = blockIdx.x & 15;
    const int ublk = blockIdx.x >> 4;
    const int u0 = ublk << 7;
    const int h = tid >> 7;
    const int sl = tid & 127;
    const int s0 = sl * 4;
    const float w0 = usw[0], w1 = usw[1], w2 = usw[2], sb = sbp[0], fdb = fdbp[0];
    const float ub0 = sb + w1;
    const float ub1 = sb + w0 * (1.f / 3.f) + w1 * (2.f / 3.f);
    const float ub2 = sb + w0 * (2.f / 3.f) + w1 * (1.f / 3.f) + w2;
    const int bsb = b * S_N + s0;
    float4 cap[4], cr[4]; unsigned fq[4];
    #pragma unroll
    for (int j = 0; j < 4; ++j) {
        cap[j] = ((const float4*)capA)[bsb + j];
        float4 iv = ((const float4*)invA)[bsb + j];
        cr[j] = make_float4(cap[j].x * iv.x, cap[j].y * iv.y, cap[j].z * iv.z, cap[j].w * iv.w);
        fq[j] = fdm_[bsb + j];
    }
    ull k[4] = {0ULL, 0ULL, 0ULL, 0ULL};
    float e[4] = {0.f, 0.f, 0.f, 0.f};
    const int gub = b * U_N + u0 + h * 16;
    const _Float16* qkbase = qkh + ((size_t)gub) * S_N + s0;
    const int cwbase = gub * 16 + (sl >> 3);
    const int nsh = (sl & 7) * 4;
    #pragma unroll 2
    for (int uu = 0; uu < 16; ++uu) {
        const int gu = gub + uu;
        const unsigned rcu = rcArr[gu];
        if (rcu < 3u) {
            const f16x4 qv = *(const f16x4*)(qkbase + (size_t)uu * S_N);
            const float4 qmv = ((const float4*)qm4)[gu];
            const float4 ndv = ((const float4*)nds)[gu];
            const unsigned snu = seenArr[gu];
            const uint4 al = alloc3[gu];
            const unsigned nib = connU32[cwbase + uu * 16] >> nsh;
            const float add = (rcu == 0u) ? ub0 : ((rcu == 1u) ? ub1 : ub2);
            const unsigned uinv = ~(unsigned)(u0 + h * 16 + uu);
            #pragma unroll
            for (int j = 0; j < 4; ++j) {
                const unsigned us = (unsigned)(s0 + j);
                const bool ful = (cap[j].x >= ndv.x) & (cap[j].y >= ndv.y) &
                                 (cap[j].z >= ndv.z) & (cap[j].w >= ndv.w);
                const bool aok = (al.x != us) & (al.y != us) & (al.z != us);
                const bool el = (((nib >> j) & 1u) != 0u) & ful & aok;
                const float lg = (float)qv[j] + qmv.x * cr[j].x + qmv.y * cr[j].y +
                                 qmv.z * cr[j].z + qmv.w * cr[j].w + add +
                                 (((snu & fq[j]) == 0u) ? fdb : 0.f);
                if (el) {
                    const ull kk = ((ull)monof(lg) << 32) | uinv;
                    k[j] = k[j] > kk ? k[j] : kk;
                    e[j] += __expf(lg);
                }
            }
        }
    }
    __shared__ ull mk[8][128][4];
    __shared__ float me[8][128][4];
    #pragma unroll
    for (int j = 0; j < 4; ++j) { mk[h][sl][j] = k[j]; me[h][sl][j] = e[j]; }
    __syncthreads();
    if (tid < 512) {
        const int sl2 = tid >> 2, j2 = tid & 3;
        ull kb2 = mk[0][sl2][j2];
        float eb = me[0][sl2][j2];
        #pragma unroll
        for (int o = 1; o < 8; ++o) {
            const ull kk = mk[o][sl2][j2];
            kb2 = kk > kb2 ? kk : kb2;
            eb += me[o][sl2][j2];
        }
        const size_t p = (size_t)ublk * (B_N * S_N) + (size_t)b * S_N + sl2 * 4 + j2;
        keypart[p] = kb2;
        sumpart[p] = eb;
    }
}

__global__ __launch_bounds__(1024) void iter_midapply(
    const ull* __restrict__ keypart, const float* __restrict__ sumpart,
    const unsigned* __restrict__ fdm_, const float* __restrict__ nds,
    uint4* __restrict__ alloc3, unsigned* __restrict__ allocU,
    unsigned* __restrict__ rcArr, unsigned* __restrict__ seenArr,
    float* __restrict__ capA, float* __restrict__ logp,
    unsigned* __restrict__ any_valid, int iter) {
    if (iter > 0 && any_valid[iter - 1] == 0u) return;
    __shared__ ull ukeyL[2048];
    __shared__ unsigned sgL[2048];
    __shared__ ull bkL[512];
    __shared__ float bsL[512];
    __shared__ float lpL[512];
    const int b = blockIdx.x, t = threadIdx.x;
    ukeyL[t] = 0ULL; ukeyL[t + 1024] = 0ULL;
    sgL[t] = 0u; sgL[t + 1024] = 0u;
    __syncthreads();
    const int s = t & 511, h = t >> 9;
    const int base = b * S_N + s;
    ull best = 0ULL; float ssum = 0.f;
    #pragma unroll
    for (int j = h * 8; j < h * 8 + 8; ++j) {
        const ull kk = keypart[(size_t)j * (B_N * S_N) + base];
        best = kk > best ? kk : best;
        ssum += sumpart[(size_t)j * (B_N * S_N) + base];
    }
    if (h == 0) { bkL[s] = best; bsL[s] = ssum; }
    __syncthreads();
    unsigned prop = 0u;
    if (h == 1) {
        const ull ob = bkL[s];
        best = ob > best ? ob : best;
        ssum += bsL[s];
        if (best != 0ULL) {
            const float mx = unmonof((unsigned)(best >> 32));
            const unsigned pu = ~(unsigned)best;
            lpL[s] = mx - __logf(ssum);
            const ull pk = ((ull)monof(mx) << 32) | (~(unsigned)s);
            atomicMax(&ukeyL[pu], pk);
            atomicOr(&sgL[pu], fdm_[base]);
            prop = 1u;
        }
    }
    const ull bal = __ballot(prop != 0u);
    if (bal != 0ULL && (t & 63) == 0) atomicOr(&any_valid[iter], 1u);
    __syncthreads();
    #pragma unroll
    for (int g = 0; g < 2; ++g) {
        const int u = t + g * 1024;
        const ull key = ukeyL[u];
        if (key != 0ULL) {
            const int gu = b * U_N + u;
            const unsigned s2 = ~(unsigned)key;
            const int bs2 = b * S_N + (int)s2;
            uint4 al = alloc3[gu];
            const unsigned r = rcArr[gu];
            if (r == 0u) al.x = s2; else if (r == 1u) al.y = s2; else al.z = s2;
            alloc3[gu] = al;
            allocU[gu * 16 + (s2 >> 5)] |= 1u << (s2 & 31u);
            const float4 nd = ((const float4*)nds)[gu];
            float4 cv = ((float4*)capA)[bs2];
            cv.x = fmaxf(cv.x - nd.x, 0.f); cv.y = fmaxf(cv.y - nd.y, 0.f);
            cv.z = fmaxf(cv.z - nd.z, 0.f); cv.w = fmaxf(cv.w - nd.w, 0.f);
            ((float4*)capA)[bs2] = cv;
            rcArr[gu] = r + 1u;
            logp[gu] += lpL[s2];
            seenArr[gu] |= sgL[u];
        }
    }
}

__global__ void finalize_logp(const float* __restrict__ logp, float* __restrict__ out) {
    int b = blockIdx.x, t = threadIdx.x;
    float s = 0.f;
    for (int u = t; u < U_N; u += 256) s += logp[b * U_N + u];
    #pragma unroll
    for (int m = 1; m < 64; m <<= 1) s += __shfl_xor(s, m, 64);
    __shared__ float r[4];
    if ((t & 63) == 0) r[t >> 6] = s;
    __syncthreads();
    if (t == 0) out[b] = r[0] + r[1] + r[2] + r[3];
}

__global__ void finalize_alloc(const unsigned* __restrict__ allocU, float* __restrict__ out) {
    int idx = blockIdx.x * 256 + threadIdx.x;
    int bu = idx >> 7;
    int s4 = (idx & 127) * 4;
    unsigned w = allocU[bu * 16 + (s4 >> 5)];
    float4 o;
    o.x = ((w >> ((s4 + 0) & 31)) & 1u) ? 1.f : 0.f;
    o.y = ((w >> ((s4 + 1) & 31)) & 1u) ? 1.f : 0.f;
    o.z = ((w >> ((s4 + 2) & 31)) & 1u) ? 1.f : 0.f;
    o.w = ((w >> ((s4 + 3) & 31)) & 1u) ? 1.f : 0.f;
    *(float4*)(out + 16 + (size_t)bu * S_N + s4) = o;
}

__global__ void finalize_cap(const float* __restrict__ capA, float* __restrict__ out) {
    int i = blockIdx.x * 256 + threadIdx.x;
    if (i < B_N * S_N * 4) out[16 + (size_t)B_N * U_N * S_N + i] = capA[i];
}

extern "C" void kernel_launch(void* const* d_in, const int* in_sizes, int n_in,
                              void* d_out, int out_size, void* d_ws, size_t ws_size,
                              hipStream_t stream) {
    const float* user_enc = (const float*)d_in[0];
    const float* server_enc = (const float*)d_in[1];
    const float* users = (const float*)d_in[2];
    const float* servers = (const float*)d_in[3];
    const int* connect = (const int*)d_in[4];
    const int* fd_onehot = (const int*)d_in[5];
    const float* state_proj_w = (const float*)d_in[6];
    const float* state_proj_b = (const float*)d_in[7];
    const float* fd_bias = (const float*)d_in[8];
    const float* ptr_q_w = (const float*)d_in[9];
    const float* ptr_k_w = (const float*)d_in[10];
    const float* user_state_w = (const float*)d_in[11];
    const float* score_bias = (const float*)d_in[12];
    float* out = (float*)d_out;

    char* w = (char*)d_ws;
    _Float16* qkh = (_Float16*)(w + 0);                    // (B,U,S) fp16  33554432 B
    unsigned short* qb = (unsigned short*)(w + 33554432);  // (B,U,D) bf16   8388608 B
    unsigned short* kb = (unsigned short*)(w + 41943040);  // (B,S,D) bf16   2097152 B
    ull* keypart = (ull*)(w + 44040192);                   // (16,B*S)       1048576 B
    float* sumpart = (float*)(w + 45088768);               // (16,B*S)        524288 B
    float* qm = (float*)(w + 45613056);                    // (B,U,4)         524288 B
    ull* connU = (ull*)(w + 46137344);                     // (B,U,8)        2097152 B
    unsigned* allocU = (unsigned*)(w + 48234496);          // (B,U,16)       2097152 B
    uint4* alloc3 = (uint4*)(w + 50331648);                // (B,U)           524288 B
    float* nds = (float*)(w + 50855936);                   // (B,U,4)         524288 B
    unsigned* fdm = (unsigned*)(w + 51380224);             // (B,S)            32768 B
    float* capA = (float*)(w + 51412992);                  // (B,S,4)         131072 B
    float* invA = (float*)(w + 51544064);                  // (B,S,4)         131072 B
    unsigned* rcArr = (unsigned*)(w + 51675136);           // (B,U)           131072 B
    unsigned* seenArr = (unsigned*)(w + 51806208);         // (B,U)           131072 B
    float* logp = (float*)(w + 51937280);                  // (B,U)           131072 B
    float* M3 = (float*)(w + 52068352);                    // (D,4)             2048 B
    unsigned* any_valid = (unsigned*)(w + 52070400);       // 16

    init_state<<<2048, 256, 0, stream>>>(servers, users, fd_onehot, allocU, alloc3, rcArr,
                                         seenArr, logp, capA, invA, fdm, nds, any_valid);
    pack_connect<<<8192, 256, 0, stream>>>(connect, connU);
    gemm_nt<true, 1><<<dim3(8, 2, 16), 256, 0, stream>>>(server_enc, ptr_k_w, state_proj_b,
                                                         nullptr, kb, S_N, D_N, D_N, INV_SQRT_D);
    gemm_nt<false, 1><<<dim3(32, 2, 16), 256, 0, stream>>>(user_enc, ptr_q_w, nullptr,
                                                           nullptr, qb, U_N, D_N, D_N, 1.0f);
    m3_kernel<<<1, 512, 0, stream>>>(ptr_k_w, state_proj_w, ptr_q_w, M3);
    qm_kernel<<<dim3(32, 16), 256, 0, stream>>>(user_enc, M3, qm);
    qk_mfma<<<dim3(16, 8, 16), 256, 0, stream>>>(qb, kb, qkh);

    // Fused cooperative iteration loop (256 blocks x 1024 thr = 1 block/CU)
    const unsigned* connU32c = (const unsigned*)connU;
    void* args[] = {(void*)&qkh, (void*)&qm, (void*)&nds, (void*)&connU32c,
                    (void*)&alloc3, (void*)&allocU, (void*)&rcArr, (void*)&seenArr,
                    (void*)&fdm, (void*)&capA, (void*)&invA,
                    (void*)&user_state_w, (void*)&score_bias, (void*)&fd_bias,
                    (void*)&keypart, (void*)&sumpart, (void*)&logp, (void*)&any_valid,
                    (void*)&out};
    hipError_t cerr = hipLaunchCooperativeKernel((const void*)alloc_loop, dim3(256), dim3(1024),
                                                 args, 0, stream);
    if (cerr != hipSuccess) {
        (void)hipGetLastError();  // clear sticky error; fall back to multi-launch loop
        for (int it = 0; it < 16; ++it) {
            iter_score<<<256, 1024, 0, stream>>>(qkh, qm, nds, (const unsigned*)connU, alloc3,
                                                 rcArr, seenArr, fdm, capA, invA, user_state_w,
                                                 score_bias, fd_bias, keypart, sumpart,
                                                 any_valid, it);
            iter_midapply<<<16, 1024, 0, stream>>>(keypart, sumpart, fdm, nds, alloc3, allocU,
                                                   rcArr, seenArr, capA, logp, any_valid, it);
        }
        finalize_logp<<<16, 256, 0, stream>>>(logp, out);
        finalize_alloc<<<16384, 256, 0, stream>>>(allocU, out);
        finalize_cap<<<128, 256, 0, stream>>>(capA, out);
    }
}

// Round 3
// 585.126 us; speedup vs baseline: 1.5997x; 1.5997x over previous
//
#include <hip/hip_runtime.h>
#include <hip/hip_bf16.h>

#define B_N 16
#define U_N 2048
#define S_N 512
#define D_N 128
#define INV_SQRT_D 0.08838834764831845f

typedef unsigned long long ull;
typedef __attribute__((ext_vector_type(8))) short bf16x8;
typedef __attribute__((ext_vector_type(4))) float f32x4;
typedef __attribute__((ext_vector_type(4))) _Float16 f16x4;

// ---------- helpers ----------
__device__ __forceinline__ unsigned monof(float v) {
    unsigned b = __float_as_uint(v);
    return (b & 0x80000000u) ? ~b : (b | 0x80000000u);
}
__device__ __forceinline__ float unmonof(unsigned m) {
    unsigned b = (m & 0x80000000u) ? (m & 0x7fffffffu) : ~m;
    return __uint_as_float(b);
}
__device__ __forceinline__ unsigned short f2bf(float x) {  // RNE fp32->bf16
    unsigned u = __float_as_uint(x);
    return (unsigned short)((u + 0x7fffu + ((u >> 16) & 1u)) >> 16);
}

// ---------- init: zero state, pack needs/caps/fd masks, zero out-scalars + barriers ----------
__global__ void init_state(const float* __restrict__ servers, const float* __restrict__ users,
                           const int* __restrict__ fd_onehot,
                           unsigned* allocU, uint4* alloc3, unsigned* rcArr, unsigned* seenArr,
                           float* logp, float* capA, float* invA, unsigned* fdm, float* nds,
                           unsigned* any_valid, unsigned* bar, float* out) {
    int i = blockIdx.x * 256 + threadIdx.x;  // 2048 blocks -> 524288 threads
    if (i < B_N * U_N * 16) allocU[i] = 0u;
    if (i < B_N * U_N) {
        rcArr[i] = 0u; seenArr[i] = 0u; logp[i] = 0.f;
        alloc3[i] = make_uint4(0xFFFFFFFFu, 0xFFFFFFFFu, 0xFFFFFFFFu, 0xFFFFFFFFu);
        const float* up = users + (size_t)i * 6;
        nds[i * 4 + 0] = up[2]; nds[i * 4 + 1] = up[3];
        nds[i * 4 + 2] = up[4]; nds[i * 4 + 3] = up[5];
    }
    if (i < B_N * S_N) {
        const float* sp = servers + (size_t)i * 7;
        float4 c = make_float4(sp[3], sp[4], sp[5], sp[6]);
        ((float4*)capA)[i] = c;
        ((float4*)invA)[i] = make_float4(1.f / fmaxf(c.x, 1e-6f), 1.f / fmaxf(c.y, 1e-6f),
                                         1.f / fmaxf(c.z, 1e-6f), 1.f / fmaxf(c.w, 1e-6f));
        unsigned w = 0u;
        const int* fp = fd_onehot + (size_t)i * 32;
        #pragma unroll
        for (int f = 0; f < 32; ++f) w |= (fp[f] != 0 ? 1u : 0u) << f;
        fdm[i] = w;
    }
    if (i < 16) { any_valid[i] = 0u; out[i] = 0.f; }
    if (i < 256) bar[i] = 0u;
}

// ---------- pack connect (B,U,S) int32 -> (B,U,S-bits): ballot per wave ----------
__global__ void pack_connect(const int* __restrict__ connect, ull* __restrict__ connU) {
    int i = blockIdx.x * 4 + (threadIdx.x >> 6);  // row index in [0, B*U)
    int lane = threadIdx.x & 63;
    const int* row = connect + (size_t)i * S_N;
    #pragma unroll
    for (int c = 0; c < 8; ++c) {
        ull m = __ballot(row[c * 64 + lane] != 0);
        if (lane == 0) connU[(size_t)i * 8 + c] = m;
    }
}

// ---------- generic fp32 GEMM: C[z][m][n] = scale * sum_k (A[z][m][k](+abias[k])) * B[n][k]
template <bool ABIAS, int OUTMODE>
__global__ __launch_bounds__(256) void gemm_nt(const float* __restrict__ A, const float* __restrict__ Bm,
                                               const float* __restrict__ abias, float* __restrict__ C,
                                               unsigned short* __restrict__ C16,
                                               int M, int N, int K, float scale) {
    __shared__ float As[16][68];
    __shared__ float Bs[16][68];
    int z = blockIdx.z;
    const float* Ab = A + (size_t)z * M * K;
    const float* Bb = Bm;
    int m0 = blockIdx.x * 64, n0 = blockIdx.y * 64;
    int tid = threadIdx.x;
    int tx = tid & 15, ty = tid >> 4;
    int lrow = tid >> 2, lk = (tid & 3) * 4;
    float acc[4][4] = {};
    for (int k0 = 0; k0 < K; k0 += 16) {
        float4 av = *(const float4*)(Ab + (size_t)(m0 + lrow) * K + k0 + lk);
        float4 bv = *(const float4*)(Bb + (size_t)(n0 + lrow) * K + k0 + lk);
        if (ABIAS) {
            av.x += abias[k0 + lk]; av.y += abias[k0 + lk + 1];
            av.z += abias[k0 + lk + 2]; av.w += abias[k0 + lk + 3];
        }
        __syncthreads();
        As[lk + 0][lrow] = av.x; As[lk + 1][lrow] = av.y; As[lk + 2][lrow] = av.z; As[lk + 3][lrow] = av.w;
        Bs[lk + 0][lrow] = bv.x; Bs[lk + 1][lrow] = bv.y; Bs[lk + 2][lrow] = bv.z; Bs[lk + 3][lrow] = bv.w;
        __syncthreads();
        #pragma unroll
        for (int kk = 0; kk < 16; ++kk) {
            float4 a = *(const float4*)&As[kk][ty * 4];
            float4 bq = *(const float4*)&Bs[kk][tx * 4];
            float ar[4] = {a.x, a.y, a.z, a.w}, br[4] = {bq.x, bq.y, bq.z, bq.w};
            #pragma unroll
            for (int ii = 0; ii < 4; ++ii)
                #pragma unroll
                for (int jj = 0; jj < 4; ++jj) acc[ii][jj] += ar[ii] * br[jj];
        }
    }
    #pragma unroll
    for (int ii = 0; ii < 4; ++ii) {
        float4 o = make_float4(acc[ii][0] * scale, acc[ii][1] * scale,
                               acc[ii][2] * scale, acc[ii][3] * scale);
        size_t idx = (size_t)z * M * N + (size_t)(m0 + ty * 4 + ii) * N + n0 + tx * 4;
        if (OUTMODE != 1) *(float4*)(C + idx) = o;
        if (OUTMODE != 0) {
            ushort4 ob;
            ob.x = f2bf(o.x); ob.y = f2bf(o.y); ob.z = f2bf(o.z); ob.w = f2bf(o.w);
            *(ushort4*)(C16 + idx) = ob;
        }
    }
}

// ---------- M3[e][c] = sum_d ptr_q_w[d,e] * (inv_sqrt_d * sum_f ptr_k_w[d,f]*state_proj_w[f,c]) ----
__global__ void m3_kernel(const float* __restrict__ kw, const float* __restrict__ spw,
                          const float* __restrict__ qw, float* __restrict__ M3) {
    __shared__ float M2s[512];
    int t = threadIdx.x;
    {
        int d = t >> 2, c = t & 3;
        float acc = 0.f;
        for (int e = 0; e < 128; ++e) acc += kw[d * 128 + e] * spw[e * 4 + c];
        M2s[d * 4 + c] = acc * INV_SQRT_D;
    }
    __syncthreads();
    {
        int e = t >> 2, c = t & 3;
        float acc = 0.f;
        for (int d = 0; d < 128; ++d) acc += qw[d * 128 + e] * M2s[d * 4 + c];
        M3[e * 4 + c] = acc;
    }
}

// ---------- qm[b,u,c] = sum_e user_enc[b,u,e]*M3[e,c] ----------
__global__ void qm_kernel(const float* __restrict__ enc, const float* __restrict__ M3, float* __restrict__ qm) {
    __shared__ float qs[64][129];
    __shared__ float m3s[512];
    int b = blockIdx.y, u0 = blockIdx.x * 64;
    int t = threadIdx.x;
    for (int i = t; i < 512; i += 256) m3s[i] = M3[i];
    #pragma unroll
    for (int it = 0; it < 8; ++it) {
        int f4 = t + 256 * it;
        int row = f4 >> 5;
        int col = (f4 & 31) * 4;
        float4 v = *(const float4*)(enc + ((size_t)(b * U_N + u0 + row)) * D_N + col);
        qs[row][col] = v.x; qs[row][col + 1] = v.y; qs[row][col + 2] = v.z; qs[row][col + 3] = v.w;
    }
    __syncthreads();
    int ul = t >> 2, c = t & 3;
    float acc = 0.f;
    for (int d = 0; d < 128; ++d) acc += qs[ul][d] * m3s[d * 4 + c];
    qm[((size_t)(b * U_N + u0 + ul)) * 4 + c] = acc;
}

// ---------- qk MFMA: qkh[b][u][s] = fp16( sum_k qb[b][u][k]*kb[b][s][k] ), bf16 inputs. ----------
__global__ __launch_bounds__(256) void qk_mfma(const unsigned short* __restrict__ qb,
                                               const unsigned short* __restrict__ kb,
                                               _Float16* __restrict__ qkh) {
    const int b = blockIdx.z, u0 = blockIdx.x * 128, s0 = blockIdx.y * 64;
    const int t = threadIdx.x, w = t >> 6, l = t & 63;
    const int lr = l & 15, lq = l >> 4;
    const unsigned short* Ab = qb + ((size_t)(b * U_N + u0 + w * 32 + lr)) * D_N + lq * 8;
    const unsigned short* Bb = kb + ((size_t)(b * S_N + s0 + lr)) * D_N + lq * 8;
    f32x4 acc[2][4] = {};
    #pragma unroll
    for (int kt = 0; kt < 4; ++kt) {
        bf16x8 a0 = *(const bf16x8*)(Ab + kt * 32);
        bf16x8 a1 = *(const bf16x8*)(Ab + 16 * D_N + kt * 32);
        #pragma unroll
        for (int c = 0; c < 4; ++c) {
            bf16x8 bf = *(const bf16x8*)(Bb + c * 16 * D_N + kt * 32);
            acc[0][c] = __builtin_amdgcn_mfma_f32_16x16x32_bf16(a0, bf, acc[0][c], 0, 0, 0);
            acc[1][c] = __builtin_amdgcn_mfma_f32_16x16x32_bf16(a1, bf, acc[1][c], 0, 0, 0);
        }
    }
    __shared__ _Float16 Cs[128][72];
    #pragma unroll
    for (int mt = 0; mt < 2; ++mt)
        #pragma unroll
        for (int c = 0; c < 4; ++c)
            #pragma unroll
            for (int r = 0; r < 4; ++r)
                Cs[w * 32 + mt * 16 + lq * 4 + r][c * 16 + lr] = (_Float16)acc[mt][c][r];
    __syncthreads();
    #pragma unroll
    for (int k = 0; k < 4; ++k) {
        int row = (t >> 3) + k * 32;
        int sg = (t & 7) * 8;
        uint4 v = *(const uint4*)&Cs[row][sg];
        *(uint4*)(qkh + ((size_t)(b * U_N + u0 + row)) * S_N + s0 + sg) = v;
    }
}

// =====================================================================================
// Fused iteration loop v2: 256 blocks x 1024 threads, cooperative (residency guarantee)
// but NO grid.sync — one per-batch 16-block spin barrier per iteration; apply phase is
// computed redundantly by all 16 blocks of a batch. qkh slice in registers; per-user
// state in LDS; per-server caps in registers. Per-iter global traffic = partials only.
// =====================================================================================
__global__ __launch_bounds__(1024) void alloc_loop2(
    const _Float16* __restrict__ qkh, const float* __restrict__ qm4,
    const float* __restrict__ nds, const unsigned* __restrict__ connU32,
    const unsigned* __restrict__ fdm_, const float* __restrict__ capA,
    const float* __restrict__ invA, const float* __restrict__ usw,
    const float* __restrict__ sbp, const float* __restrict__ fdbp,
    ull* __restrict__ keypartI, float* __restrict__ sumpartI,
    unsigned* __restrict__ bar, float* __restrict__ out) {
    __shared__ __align__(16) char smem[65040];
    // score/apply overlay [0, 49152)
    ull (*mk)[128][4] = (ull (*)[128][4])smem;               // 32768
    float (*me)[128][4] = (float (*)[128][4])(smem + 32768); // 16384
    ull* ukeyL = (ull*)smem;                                 // 16384
    unsigned* sgL = (unsigned*)(smem + 16384);               //  8192
    ull* bkL = (ull*)(smem + 24576);                         //  4096
    float* bsL = (float*)(smem + 28672);                     //  2048
    float* lpL = (float*)(smem + 30720);                     //  2048
    // persistent per-block state [49152, 65040)
    float4* qmL = (float4*)(smem + 49152);                   // 128 users  2048
    float4* ndL = (float4*)(smem + 51200);                   // 2048
    uint4* alL = (uint4*)(smem + 53248);                     // 2048
    unsigned* rcL = (unsigned*)(smem + 55296);               // 512
    unsigned* seenL = (unsigned*)(smem + 55808);             // 512
    float* lpUL = (float*)(smem + 56320);                    // 512
    float4* ivL = (float4*)(smem + 56832);                   // 512 servers 8192
    unsigned* anyL = (unsigned*)(smem + 65024);              // 4

    const int tid = threadIdx.x;
    const int b = blockIdx.x & 15;        // consecutive blocks -> different b; blocks of a
    const int ublk = blockIdx.x >> 4;     // batch land on one XCD under %8 round-robin
    const int u0 = ublk << 7;
    const int h = tid >> 7;               // user octant (16 users)
    const int sl = tid & 127;             // server quad: 4sl..4sl+3
    const int s0 = sl * 4;
    const float w0 = usw[0], w1 = usw[1], w2 = usw[2], sb = sbp[0], fdb = fdbp[0];
    const float ub0 = sb + w1;
    const float ub1 = sb + w0 * (1.f / 3.f) + w1 * (2.f / 3.f);
    const float ub2 = sb + w0 * (2.f / 3.f) + w1 * (1.f / 3.f) + w2;
    const int bsb = b * S_N + s0;
    const int gub = b * U_N + u0 + h * 16;

    // ---- iteration-invariant init ----
    if (tid < 128) {
        const int gu = b * U_N + u0 + tid;
        qmL[tid] = ((const float4*)qm4)[gu];
        ndL[tid] = ((const float4*)nds)[gu];
        alL[tid] = make_uint4(0xFFFFFFFFu, 0xFFFFFFFFu, 0xFFFFFFFFu, 0xFFFFFFFFu);
        rcL[tid] = 0u; seenL[tid] = 0u; lpUL[tid] = 0.f;
    }
    if (tid < 512) ivL[tid] = ((const float4*)invA)[b * S_N + tid];
    if (tid == 0) *anyL = 1u;
    float4 cap[4]; unsigned fq[4];
    #pragma unroll
    for (int j = 0; j < 4; ++j) {
        cap[j] = ((const float4*)capA)[bsb + j];
        fq[j] = fdm_[bsb + j];
    }
    const int cwbase = gub * 16 + (sl >> 3);
    const int nsh = (sl & 7) * 4;
    ull connbits = 0ULL;
    #pragma unroll
    for (int uu = 0; uu < 16; ++uu)
        connbits |= (ull)((connU32[cwbase + uu * 16] >> nsh) & 0xFu) << (4 * uu);
    const _Float16* qkbase = qkh + (size_t)gub * S_N + s0;
    f16x4 qv[16];
    #pragma unroll
    for (int uu = 0; uu < 16; ++uu) qv[uu] = *(const f16x4*)(qkbase + (size_t)uu * S_N);
    __syncthreads();

    for (int iter = 0; iter < 16; ++iter) {
        // ===================== score =====================
        float4 cr[4];
        #pragma unroll
        for (int j = 0; j < 4; ++j) {
            const float4 iv = ivL[s0 + j];
            cr[j] = make_float4(cap[j].x * iv.x, cap[j].y * iv.y,
                                cap[j].z * iv.z, cap[j].w * iv.w);
        }
        ull k[4] = {0ULL, 0ULL, 0ULL, 0ULL};
        float e[4] = {0.f, 0.f, 0.f, 0.f};
        #pragma unroll
        for (int uu = 0; uu < 16; ++uu) {
            const int idx = h * 16 + uu;
            const unsigned rcu = rcL[idx];             // LDS broadcast within octant
            if (rcu < 3u) {
                const float4 qmv = qmL[idx];
                const float4 ndv = ndL[idx];
                const unsigned snu = seenL[idx];
                const uint4 al = alL[idx];
                const unsigned nib = (unsigned)(connbits >> (4 * uu)) & 0xFu;
                const float add = (rcu == 0u) ? ub0 : ((rcu == 1u) ? ub1 : ub2);
                const unsigned uinv = ~(unsigned)(u0 + h * 16 + uu);
                #pragma unroll
                for (int j = 0; j < 4; ++j) {
                    const unsigned us = (unsigned)(s0 + j);
                    const bool ful = (cap[j].x >= ndv.x) & (cap[j].y >= ndv.y) &
                                     (cap[j].z >= ndv.z) & (cap[j].w >= ndv.w);
                    const bool aok = (al.x != us) & (al.y != us) & (al.z != us);
                    const bool el = (((nib >> j) & 1u) != 0u) & ful & aok;
                    const float lg = (float)qv[uu][j] + qmv.x * cr[j].x + qmv.y * cr[j].y +
                                     qmv.z * cr[j].z + qmv.w * cr[j].w + add +
                                     (((snu & fq[j]) == 0u) ? fdb : 0.f);
                    if (el) {
                        const ull kk = ((ull)monof(lg) << 32) | uinv;
                        k[j] = k[j] > kk ? k[j] : kk;
                        e[j] += __expf(lg);
                    }
                }
            }
        }
        #pragma unroll
        for (int j = 0; j < 4; ++j) { mk[h][sl][j] = k[j]; me[h][sl][j] = e[j]; }
        __syncthreads();
        if (tid < 512) {
            const int sl2 = tid >> 2, j2 = tid & 3;
            ull kb2 = mk[0][sl2][j2];
            float eb = me[0][sl2][j2];
            #pragma unroll
            for (int o = 1; o < 8; ++o) {
                const ull kk = mk[o][sl2][j2];
                kb2 = kk > kb2 ? kk : kb2;
                eb += me[o][sl2][j2];
            }
            const size_t p = (size_t)iter * (16 * B_N * S_N) +
                             (size_t)ublk * (B_N * S_N) + (size_t)b * S_N + tid;
            keypartI[p] = kb2;
            sumpartI[p] = eb;
        }
        // ===================== per-batch 16-block barrier =====================
        __syncthreads();                    // drains vmcnt: partial stores are in L2
        if (tid == 0) {
            __threadfence();                // agent release (flush to coherence point)
            atomicAdd(&bar[b * 16 + iter], 1u);
            while (__hip_atomic_load(&bar[b * 16 + iter], __ATOMIC_RELAXED,
                                     __HIP_MEMORY_SCOPE_AGENT) < 16u)
                __builtin_amdgcn_s_sleep(2);
            __threadfence();                // agent acquire (invalidate stale)
        }
        __syncthreads();
        // ===================== apply (redundant in all 16 blocks of batch) ============
        ukeyL[tid] = 0ULL; ukeyL[tid + 1024] = 0ULL;
        sgL[tid] = 0u; sgL[tid + 1024] = 0u;
        if (tid == 0) *anyL = 0u;
        __syncthreads();
        const int s = tid & 511, hh = tid >> 9;
        const ull* kp = keypartI + (size_t)iter * (16 * B_N * S_N) + (size_t)b * S_N + s;
        const float* sp = sumpartI + (size_t)iter * (16 * B_N * S_N) + (size_t)b * S_N + s;
        ull best = 0ULL; float ssum = 0.f;
        #pragma unroll
        for (int j = hh * 8; j < hh * 8 + 8; ++j) {
            const ull kk = kp[(size_t)j * (B_N * S_N)];
            best = kk > best ? kk : best;
            ssum += sp[(size_t)j * (B_N * S_N)];
        }
        if (hh == 0) { bkL[s] = best; bsL[s] = ssum; }
        __syncthreads();
        if (hh == 1) {
            const ull ob = bkL[s];
            best = ob > best ? ob : best;
            ssum += bsL[s];
            bkL[s] = best;                  // final per-server best (for cap updates)
            if (best != 0ULL) {
                const float mx = unmonof((unsigned)(best >> 32));
                const unsigned pu = ~(unsigned)best;   // winning user (ties -> smallest u)
                lpL[s] = mx - __logf(ssum);            // max - logsumexp
                const ull pk = ((ull)monof(mx) << 32) | (~(unsigned)s);
                atomicMax(&ukeyL[pu], pk);
                atomicOr(&sgL[pu], fdm_[b * S_N + s]);
                *anyL = 1u;                  // benign race: all writers store 1
            }
        }
        __syncthreads();
        // user-state updates: only this block's 128-user slice
        #pragma unroll
        for (int g = 0; g < 2; ++g) {
            const int u = tid + g * 1024;
            if ((u >> 7) == ublk) {
                const ull key = ukeyL[u];
                if (key != 0ULL) {                     // user received >=1 proposal -> accepts
                    const int idx = u & 127;
                    const unsigned s2 = ~(unsigned)key; // accepted server (ties -> smallest s)
                    uint4 al = alL[idx];
                    const unsigned r = rcL[idx];
                    if (r == 0u) al.x = s2; else if (r == 1u) al.y = s2; else al.z = s2;
                    alL[idx] = al;
                    rcL[idx] = r + 1u;
                    seenL[idx] |= sgL[u];
                    lpUL[idx] += lpL[s2];
                }
            }
        }
        // cap updates: each thread its own 4 servers (redundant across octants/blocks)
        #pragma unroll
        for (int j = 0; j < 4; ++j) {
            const int sj = s0 + j;
            const ull bb = bkL[sj];
            if (bb != 0ULL) {
                const unsigned pu = ~(unsigned)bb;
                if ((~(unsigned)ukeyL[pu]) == (unsigned)sj) {   // server's proposal accepted
                    const float4 nd = ((const float4*)nds)[b * U_N + pu];
                    cap[j].x = fmaxf(cap[j].x - nd.x, 0.f);
                    cap[j].y = fmaxf(cap[j].y - nd.y, 0.f);
                    cap[j].z = fmaxf(cap[j].z - nd.z, 0.f);
                    cap[j].w = fmaxf(cap[j].w - nd.w, 0.f);
                }
            }
        }
        __syncthreads();
        if (*anyL == 0u) break;            // batch frozen: identical decision in all 16 blocks
    }
    // ===================== finalize (folded) =====================
    // alloc one-hot for this block's 128 users
    const size_t orow = 16 + (size_t)(b * U_N + u0) * S_N;
    for (int i2 = tid; i2 < 128 * 128; i2 += 1024) {
        const int row = i2 >> 7;
        const unsigned c4 = (unsigned)((i2 & 127) * 4);
        const uint4 al = alL[row];
        float4 o;
        o.x = (al.x == c4 + 0u || al.y == c4 + 0u || al.z == c4 + 0u) ? 1.f : 0.f;
        o.y = (al.x == c4 + 1u || al.y == c4 + 1u || al.z == c4 + 1u) ? 1.f : 0.f;
        o.z = (al.x == c4 + 2u || al.y == c4 + 2u || al.z == c4 + 2u) ? 1.f : 0.f;
        o.w = (al.x == c4 + 3u || al.y == c4 + 3u || al.z == c4 + 3u) ? 1.f : 0.f;
        *(float4*)(out + orow + (size_t)row * S_N + c4) = o;
    }
    // logp partial sum -> atomicAdd (out[b] zeroed by init_state)
    float sacc = (tid < 128) ? lpUL[tid] : 0.f;
    #pragma unroll
    for (int m = 1; m < 64; m <<= 1) sacc += __shfl_xor(sacc, m, 64);
    if ((tid & 63) == 0) bsL[tid >> 6] = sacc;
    __syncthreads();
    if (tid == 0) {
        float tt = 0.f;
        #pragma unroll
        for (int i2 = 0; i2 < 16; ++i2) tt += bsL[i2];
        atomicAdd(&out[b], tt);
    }
    // caps: ublk==0 blocks, octant 0 threads own all 512 server quads
    if (ublk == 0 && h == 0) {
        float* cdst = out + 16 + (size_t)B_N * U_N * S_N + (size_t)b * S_N * 4 + (size_t)s0 * 4;
        *(float4*)(cdst + 0) = cap[0];
        *(float4*)(cdst + 4) = cap[1];
        *(float4*)(cdst + 8) = cap[2];
        *(float4*)(cdst + 12) = cap[3];
    }
}

// =====================================================================================
// Fallback path (only if cooperative launch unavailable): round-1 proven kernels
// =====================================================================================
__global__ __launch_bounds__(1024, 1) void iter_score(
    const _Float16* __restrict__ qkh, const float* __restrict__ qm4,
    const float* __restrict__ nds, const unsigned* __restrict__ connU32,
    const uint4* __restrict__ alloc3, const unsigned* __restrict__ rcArr,
    const unsigned* __restrict__ seenArr, const unsigned* __restrict__ fdm_,
    const float* __restrict__ capA, const float* __restrict__ invA,
    const float* __restrict__ usw, const float* __restrict__ sbp, const float* __restrict__ fdbp,
    ull* __restrict__ keypart, float* __restrict__ sumpart,
    const unsigned* __restrict__ any_valid, int iter) {
    if (iter > 0 && any_valid[iter - 1] == 0u) return;
    const int tid = threadIdx.x;
    const int b = blockIdx.x & 15;
    const int ublk = blockIdx.x >> 4;
    const int u0 = ublk << 7;
    const int h = tid >> 7;
    const int sl = tid & 127;
    const int s0 = sl * 4;
    const float w0 = usw[0], w1 = usw[1], w2 = usw[2], sb = sbp[0], fdb = fdbp[0];
    const float ub0 = sb + w1;
    const float ub1 = sb + w0 * (1.f / 3.f) + w1 * (2.f / 3.f);
    const float ub2 = sb + w0 * (2.f / 3.f) + w1 * (1.f / 3.f) + w2;
    const int bsb = b * S_N + s0;
    float4 cap[4], cr[4]; unsigned fq[4];
    #pragma unroll
    for (int j = 0; j < 4; ++j) {
        cap[j] = ((const float4*)capA)[bsb + j];
        float4 iv = ((const float4*)invA)[bsb + j];
        cr[j] = make_float4(cap[j].x * iv.x, cap[j].y * iv.y, cap[j].z * iv.z, cap[j].w * iv.w);
        fq[j] = fdm_[bsb + j];
    }
    ull k[4] = {0ULL, 0ULL, 0ULL, 0ULL};
    float e[4] = {0.f, 0.f, 0.f, 0.f};
    const int gub = b * U_N + u0 + h * 16;
    const _Float16* qkbase = qkh + ((size_t)gub) * S_N + s0;
    const int cwbase = gub * 16 + (sl >> 3);
    const int nsh = (sl & 7) * 4;
    #pragma unroll 2
    for (int uu = 0; uu < 16; ++uu) {
        const int gu = gub + uu;
        const unsigned rcu = rcArr[gu];
        if (rcu < 3u) {
            const f16x4 qv = *(const f16x4*)(qkbase + (size_t)uu * S_N);
            const float4 qmv = ((const float4*)qm4)[gu];
            const float4 ndv = ((const float4*)nds)[gu];
            const unsigned snu = seenArr[gu];
            const uint4 al = alloc3[gu];
            const unsigned nib = connU32[cwbase + uu * 16] >> nsh;
            const float add = (rcu == 0u) ? ub0 : ((rcu == 1u) ? ub1 : ub2);
            const unsigned uinv = ~(unsigned)(u0 + h * 16 + uu);
            #pragma unroll
            for (int j = 0; j < 4; ++j) {
                const unsigned us = (unsigned)(s0 + j);
                const bool ful = (cap[j].x >= ndv.x) & (cap[j].y >= ndv.y) &
                                 (cap[j].z >= ndv.z) & (cap[j].w >= ndv.w);
                const bool aok = (al.x != us) & (al.y != us) & (al.z != us);
                const bool el = (((nib >> j) & 1u) != 0u) & ful & aok;
                const float lg = (float)qv[j] + qmv.x * cr[j].x + qmv.y * cr[j].y +
                                 qmv.z * cr[j].z + qmv.w * cr[j].w + add +
                                 (((snu & fq[j]) == 0u) ? fdb : 0.f);
                if (el) {
                    const ull kk = ((ull)monof(lg) << 32) | uinv;
                    k[j] = k[j] > kk ? k[j] : kk;
                    e[j] += __expf(lg);
                }
            }
        }
    }
    __shared__ ull mk[8][128][4];
    __shared__ float me[8][128][4];
    #pragma unroll
    for (int j = 0; j < 4; ++j) { mk[h][sl][j] = k[j]; me[h][sl][j] = e[j]; }
    __syncthreads();
    if (tid < 512) {
        const int sl2 = tid >> 2, j2 = tid & 3;
        ull kb2 = mk[0][sl2][j2];
        float eb = me[0][sl2][j2];
        #pragma unroll
        for (int o = 1; o < 8; ++o) {
            const ull kk = mk[o][sl2][j2];
            kb2 = kk > kb2 ? kk : kb2;
            eb += me[o][sl2][j2];
        }
        const size_t p = (size_t)ublk * (B_N * S_N) + (size_t)b * S_N + tid;
        keypart[p] = kb2;
        sumpart[p] = eb;
    }
}

__global__ __launch_bounds__(1024) void iter_midapply(
    const ull* __restrict__ keypart, const float* __restrict__ sumpart,
    const unsigned* __restrict__ fdm_, const float* __restrict__ nds,
    uint4* __restrict__ alloc3, unsigned* __restrict__ allocU,
    unsigned* __restrict__ rcArr, unsigned* __restrict__ seenArr,
    float* __restrict__ capA, float* __restrict__ logp,
    unsigned* __restrict__ any_valid, int iter) {
    if (iter > 0 && any_valid[iter - 1] == 0u) return;
    __shared__ ull ukeyL[2048];
    __shared__ unsigned sgL[2048];
    __shared__ ull bkL[512];
    __shared__ float bsL[512];
    __shared__ float lpL[512];
    const int b = blockIdx.x, t = threadIdx.x;
    ukeyL[t] = 0ULL; ukeyL[t + 1024] = 0ULL;
    sgL[t] = 0u; sgL[t + 1024] = 0u;
    __syncthreads();
    const int s = t & 511, h = t >> 9;
    const int base = b * S_N + s;
    ull best = 0ULL; float ssum = 0.f;
    #pragma unroll
    for (int j = h * 8; j < h * 8 + 8; ++j) {
        const ull kk = keypart[(size_t)j * (B_N * S_N) + base];
        best = kk > best ? kk : best;
        ssum += sumpart[(size_t)j * (B_N * S_N) + base];
    }
    if (h == 0) { bkL[s] = best; bsL[s] = ssum; }
    __syncthreads();
    unsigned prop = 0u;
    if (h == 1) {
        const ull ob = bkL[s];
        best = ob > best ? ob : best;
        ssum += bsL[s];
        if (best != 0ULL) {
            const float mx = unmonof((unsigned)(best >> 32));
            const unsigned pu = ~(unsigned)best;
            lpL[s] = mx - __logf(ssum);
            const ull pk = ((ull)monof(mx) << 32) | (~(unsigned)s);
            atomicMax(&ukeyL[pu], pk);
            atomicOr(&sgL[pu], fdm_[base]);
            prop = 1u;
        }
    }
    const ull bal = __ballot(prop != 0u);
    if (bal != 0ULL && (t & 63) == 0) atomicOr(&any_valid[iter], 1u);
    __syncthreads();
    #pragma unroll
    for (int g = 0; g < 2; ++g) {
        const int u = t + g * 1024;
        const ull key = ukeyL[u];
        if (key != 0ULL) {
            const int gu = b * U_N + u;
            const unsigned s2 = ~(unsigned)key;
            const int bs2 = b * S_N + (int)s2;
            uint4 al = alloc3[gu];
            const unsigned r = rcArr[gu];
            if (r == 0u) al.x = s2; else if (r == 1u) al.y = s2; else al.z = s2;
            alloc3[gu] = al;
            allocU[gu * 16 + (s2 >> 5)] |= 1u << (s2 & 31u);
            const float4 nd = ((const float4*)nds)[gu];
            float4 cv = ((float4*)capA)[bs2];
            cv.x = fmaxf(cv.x - nd.x, 0.f); cv.y = fmaxf(cv.y - nd.y, 0.f);
            cv.z = fmaxf(cv.z - nd.z, 0.f); cv.w = fmaxf(cv.w - nd.w, 0.f);
            ((float4*)capA)[bs2] = cv;
            rcArr[gu] = r + 1u;
            logp[gu] += lpL[s2];
            seenArr[gu] |= sgL[u];
        }
    }
}

__global__ void finalize_logp(const float* __restrict__ logp, float* __restrict__ out) {
    int b = blockIdx.x, t = threadIdx.x;
    float s = 0.f;
    for (int u = t; u < U_N; u += 256) s += logp[b * U_N + u];
    #pragma unroll
    for (int m = 1; m < 64; m <<= 1) s += __shfl_xor(s, m, 64);
    __shared__ float r[4];
    if ((t & 63) == 0) r[t >> 6] = s;
    __syncthreads();
    if (t == 0) out[b] = r[0] + r[1] + r[2] + r[3];
}

__global__ void finalize_alloc(const unsigned* __restrict__ allocU, float* __restrict__ out) {
    int idx = blockIdx.x * 256 + threadIdx.x;
    int bu = idx >> 7;
    int s4 = (idx & 127) * 4;
    unsigned w = allocU[bu * 16 + (s4 >> 5)];
    float4 o;
    o.x = ((w >> ((s4 + 0) & 31)) & 1u) ? 1.f : 0.f;
    o.y = ((w >> ((s4 + 1) & 31)) & 1u) ? 1.f : 0.f;
    o.z = ((w >> ((s4 + 2) & 31)) & 1u) ? 1.f : 0.f;
    o.w = ((w >> ((s4 + 3) & 31)) & 1u) ? 1.f : 0.f;
    *(float4*)(out + 16 + (size_t)bu * S_N + s4) = o;
}

__global__ void finalize_cap(const float* __restrict__ capA, float* __restrict__ out) {
    int i = blockIdx.x * 256 + threadIdx.x;
    if (i < B_N * S_N * 4) out[16 + (size_t)B_N * U_N * S_N + i] = capA[i];
}

extern "C" void kernel_launch(void* const* d_in, const int* in_sizes, int n_in,
                              void* d_out, int out_size, void* d_ws, size_t ws_size,
                              hipStream_t stream) {
    const float* user_enc = (const float*)d_in[0];
    const float* server_enc = (const float*)d_in[1];
    const float* users = (const float*)d_in[2];
    const float* servers = (const float*)d_in[3];
    const int* connect = (const int*)d_in[4];
    const int* fd_onehot = (const int*)d_in[5];
    const float* state_proj_w = (const float*)d_in[6];
    const float* state_proj_b = (const float*)d_in[7];
    const float* fd_bias = (const float*)d_in[8];
    const float* ptr_q_w = (const float*)d_in[9];
    const float* ptr_k_w = (const float*)d_in[10];
    const float* user_state_w = (const float*)d_in[11];
    const float* score_bias = (const float*)d_in[12];
    float* out = (float*)d_out;

    char* w = (char*)d_ws;
    // common buffers
    _Float16* qkh = (_Float16*)(w + 0);                    // 33554432
    unsigned short* qb = (unsigned short*)(w + 33554432);  //  8388608 -> 41943040
    unsigned short* kb = (unsigned short*)(w + 41943040);  //  2097152 -> 44040192
    float* qm = (float*)(w + 44040192);                    //   524288 -> 44564480
    ull* connU = (ull*)(w + 44564480);                     //  2097152 -> 46661632
    float* nds = (float*)(w + 46661632);                   //   524288 -> 47185920
    unsigned* fdm = (unsigned*)(w + 47185920);             //    32768 -> 47218688
    float* capA = (float*)(w + 47218688);                  //   131072 -> 47349760
    float* invA = (float*)(w + 47349760);                  //   131072 -> 47480832
    float* M3 = (float*)(w + 47480832);                    //     2048 -> 47482880
    unsigned* bar = (unsigned*)(w + 47482880);             //     1024 -> 47483904
    // coop-only per-iteration partials
    ull* keypartI = (ull*)(w + 47484928);                  // 16777216 -> 64262144
    float* sumpartI = (float*)(w + 64262144);              //  8388608 -> 72650752
    // fallback-only buffers alias the coop-only partials region (never used together)
    char* fb = w + 47484928;
    unsigned* rcArr = (unsigned*)(fb + 0);                 //   131072
    unsigned* seenArr = (unsigned*)(fb + 131072);          //   131072
    float* logp = (float*)(fb + 262144);                   //   131072
    uint4* alloc3 = (uint4*)(fb + 393216);                 //   524288
    unsigned* allocU = (unsigned*)(fb + 917504);           //  2097152
    unsigned* any_valid = (unsigned*)(fb + 3014656);       //       64
    ull* keypart = (ull*)(fb + 3145728);                   //  1048576
    float* sumpart = (float*)(fb + 4194304);               //   524288

    init_state<<<2048, 256, 0, stream>>>(servers, users, fd_onehot, allocU, alloc3, rcArr,
                                         seenArr, logp, capA, invA, fdm, nds, any_valid,
                                         bar, out);
    pack_connect<<<8192, 256, 0, stream>>>(connect, connU);
    gemm_nt<true, 1><<<dim3(8, 2, 16), 256, 0, stream>>>(server_enc, ptr_k_w, state_proj_b,
                                                         nullptr, kb, S_N, D_N, D_N, INV_SQRT_D);
    gemm_nt<false, 1><<<dim3(32, 2, 16), 256, 0, stream>>>(user_enc, ptr_q_w, nullptr,
                                                           nullptr, qb, U_N, D_N, D_N, 1.0f);
    m3_kernel<<<1, 512, 0, stream>>>(ptr_k_w, state_proj_w, ptr_q_w, M3);
    qm_kernel<<<dim3(32, 16), 256, 0, stream>>>(user_enc, M3, qm);
    qk_mfma<<<dim3(16, 8, 16), 256, 0, stream>>>(qb, kb, qkh);

    // Fused loop v2: cooperative launch for residency; per-batch spin barriers inside.
    const unsigned* connU32c = (const unsigned*)connU;
    const unsigned* fdmc = (const unsigned*)fdm;
    void* args[] = {(void*)&qkh, (void*)&qm, (void*)&nds, (void*)&connU32c,
                    (void*)&fdmc, (void*)&capA, (void*)&invA,
                    (void*)&user_state_w, (void*)&score_bias, (void*)&fd_bias,
                    (void*)&keypartI, (void*)&sumpartI, (void*)&bar, (void*)&out};
    hipError_t cerr = hipLaunchCooperativeKernel((const void*)alloc_loop2, dim3(256), dim3(1024),
                                                 args, 0, stream);
    if (cerr != hipSuccess) {
        (void)hipGetLastError();  // clear sticky error; fall back to multi-launch loop
        for (int it = 0; it < 16; ++it) {
            iter_score<<<256, 1024, 0, stream>>>(qkh, qm, nds, (const unsigned*)connU, alloc3,
                                                 rcArr, seenArr, fdm, capA, invA, user_state_w,
                                                 score_bias, fd_bias, keypart, sumpart,
                                                 any_valid, it);
            iter_midapply<<<16, 1024, 0, stream>>>(keypart, sumpart, fdm, nds, alloc3, allocU,
                                                   rcArr, seenArr, capA, logp, any_valid, it);
        }
        finalize_logp<<<16, 256, 0, stream>>>(logp, out);
        finalize_alloc<<<16384, 256, 0, stream>>>(allocU, out);
        finalize_cap<<<128, 256, 0, stream>>>(capA, out);
    }
}

// Round 4
// 417.728 us; speedup vs baseline: 2.2407x; 1.4007x over previous
//
#include <hip/hip_runtime.h>
#include <hip/hip_bf16.h>

#define B_N 16
#define U_N 2048
#define S_N 512
#define D_N 128
#define INV_SQRT_D 0.08838834764831845f

typedef unsigned long long ull;
typedef __attribute__((ext_vector_type(8))) short bf16x8;
typedef __attribute__((ext_vector_type(4))) float f32x4;
typedef __attribute__((ext_vector_type(4))) _Float16 f16x4;

// ---------- helpers ----------
__device__ __forceinline__ unsigned monof(float v) {
    unsigned b = __float_as_uint(v);
    return (b & 0x80000000u) ? ~b : (b | 0x80000000u);
}
__device__ __forceinline__ float unmonof(unsigned m) {
    unsigned b = (m & 0x80000000u) ? (m & 0x7fffffffu) : ~m;
    return __uint_as_float(b);
}
__device__ __forceinline__ unsigned short f2bf(float x) {  // RNE fp32->bf16
    unsigned u = __float_as_uint(x);
    return (unsigned short)((u + 0x7fffu + ((u >> 16) & 1u)) >> 16);
}

// ---------- init: zero state, pack needs/caps/fd masks ----------
__global__ void init_state(const float* __restrict__ servers, const float* __restrict__ users,
                           const int* __restrict__ fd_onehot,
                           uint4* alloc3, unsigned* rcArr, unsigned* seenArr,
                           float* logp, float* capA, float* invA, unsigned* fdm, float* nds,
                           unsigned* frozen, float* out) {
    int i = blockIdx.x * 256 + threadIdx.x;  // 128 blocks -> 32768 threads
    if (i < B_N * U_N) {
        rcArr[i] = 0u; seenArr[i] = 0u; logp[i] = 0.f;
        alloc3[i] = make_uint4(0xFFFFFFFFu, 0xFFFFFFFFu, 0xFFFFFFFFu, 0xFFFFFFFFu);
        const float* up = users + (size_t)i * 6;
        nds[i * 4 + 0] = up[2]; nds[i * 4 + 1] = up[3];
        nds[i * 4 + 2] = up[4]; nds[i * 4 + 3] = up[5];
    }
    if (i < B_N * S_N) {
        const float* sp = servers + (size_t)i * 7;
        float4 c = make_float4(sp[3], sp[4], sp[5], sp[6]);
        ((float4*)capA)[i] = c;
        ((float4*)invA)[i] = make_float4(1.f / fmaxf(c.x, 1e-6f), 1.f / fmaxf(c.y, 1e-6f),
                                         1.f / fmaxf(c.z, 1e-6f), 1.f / fmaxf(c.w, 1e-6f));
        unsigned w = 0u;
        const int* fp = fd_onehot + (size_t)i * 32;
        #pragma unroll
        for (int f = 0; f < 32; ++f) w |= (fp[f] != 0 ? 1u : 0u) << f;
        fdm[i] = w;
    }
    if (i < 16) { frozen[i] = 0u; out[i] = 0.f; }
}

// ---------- pack connect (B,U,S) int32 -> (B,U,S-bits): ballot per wave ----------
__global__ void pack_connect(const int* __restrict__ connect, ull* __restrict__ connU) {
    int i = blockIdx.x * 4 + (threadIdx.x >> 6);  // row index in [0, B*U)
    int lane = threadIdx.x & 63;
    const int* row = connect + (size_t)i * S_N;
    #pragma unroll
    for (int c = 0; c < 8; ++c) {
        ull m = __ballot(row[c * 64 + lane] != 0);
        if (lane == 0) connU[(size_t)i * 8 + c] = m;
    }
}

// ---------- generic fp32 GEMM: C[z][m][n] = scale * sum_k (A[z][m][k](+abias[k])) * B[n][k]
template <bool ABIAS, int OUTMODE>
__global__ __launch_bounds__(256) void gemm_nt(const float* __restrict__ A, const float* __restrict__ Bm,
                                               const float* __restrict__ abias, float* __restrict__ C,
                                               unsigned short* __restrict__ C16,
                                               int M, int N, int K, float scale) {
    __shared__ float As[16][68];
    __shared__ float Bs[16][68];
    int z = blockIdx.z;
    const float* Ab = A + (size_t)z * M * K;
    const float* Bb = Bm;
    int m0 = blockIdx.x * 64, n0 = blockIdx.y * 64;
    int tid = threadIdx.x;
    int tx = tid & 15, ty = tid >> 4;
    int lrow = tid >> 2, lk = (tid & 3) * 4;
    float acc[4][4] = {};
    for (int k0 = 0; k0 < K; k0 += 16) {
        float4 av = *(const float4*)(Ab + (size_t)(m0 + lrow) * K + k0 + lk);
        float4 bv = *(const float4*)(Bb + (size_t)(n0 + lrow) * K + k0 + lk);
        if (ABIAS) {
            av.x += abias[k0 + lk]; av.y += abias[k0 + lk + 1];
            av.z += abias[k0 + lk + 2]; av.w += abias[k0 + lk + 3];
        }
        __syncthreads();
        As[lk + 0][lrow] = av.x; As[lk + 1][lrow] = av.y; As[lk + 2][lrow] = av.z; As[lk + 3][lrow] = av.w;
        Bs[lk + 0][lrow] = bv.x; Bs[lk + 1][lrow] = bv.y; Bs[lk + 2][lrow] = bv.z; Bs[lk + 3][lrow] = bv.w;
        __syncthreads();
        #pragma unroll
        for (int kk = 0; kk < 16; ++kk) {
            float4 a = *(const float4*)&As[kk][ty * 4];
            float4 bq = *(const float4*)&Bs[kk][tx * 4];
            float ar[4] = {a.x, a.y, a.z, a.w}, br[4] = {bq.x, bq.y, bq.z, bq.w};
            #pragma unroll
            for (int ii = 0; ii < 4; ++ii)
                #pragma unroll
                for (int jj = 0; jj < 4; ++jj) acc[ii][jj] += ar[ii] * br[jj];
        }
    }
    #pragma unroll
    for (int ii = 0; ii < 4; ++ii) {
        float4 o = make_float4(acc[ii][0] * scale, acc[ii][1] * scale,
                               acc[ii][2] * scale, acc[ii][3] * scale);
        size_t idx = (size_t)z * M * N + (size_t)(m0 + ty * 4 + ii) * N + n0 + tx * 4;
        if (OUTMODE != 1) *(float4*)(C + idx) = o;
        if (OUTMODE != 0) {
            ushort4 ob;
            ob.x = f2bf(o.x); ob.y = f2bf(o.y); ob.z = f2bf(o.z); ob.w = f2bf(o.w);
            *(ushort4*)(C16 + idx) = ob;
        }
    }
}

// ---------- M3[e][c] = sum_d ptr_q_w[d,e] * (inv_sqrt_d * sum_f ptr_k_w[d,f]*state_proj_w[f,c]) ----
__global__ void m3_kernel(const float* __restrict__ kw, const float* __restrict__ spw,
                          const float* __restrict__ qw, float* __restrict__ M3) {
    __shared__ float M2s[512];
    int t = threadIdx.x;
    {
        int d = t >> 2, c = t & 3;
        float acc = 0.f;
        for (int e = 0; e < 128; ++e) acc += kw[d * 128 + e] * spw[e * 4 + c];
        M2s[d * 4 + c] = acc * INV_SQRT_D;
    }
    __syncthreads();
    {
        int e = t >> 2, c = t & 3;
        float acc = 0.f;
        for (int d = 0; d < 128; ++d) acc += qw[d * 128 + e] * M2s[d * 4 + c];
        M3[e * 4 + c] = acc;
    }
}

// ---------- qm[b,u,c] = sum_e user_enc[b,u,e]*M3[e,c] ----------
__global__ void qm_kernel(const float* __restrict__ enc, const float* __restrict__ M3, float* __restrict__ qm) {
    __shared__ float qs[64][129];
    __shared__ float m3s[512];
    int b = blockIdx.y, u0 = blockIdx.x * 64;
    int t = threadIdx.x;
    for (int i = t; i < 512; i += 256) m3s[i] = M3[i];
    #pragma unroll
    for (int it = 0; it < 8; ++it) {
        int f4 = t + 256 * it;
        int row = f4 >> 5;
        int col = (f4 & 31) * 4;
        float4 v = *(const float4*)(enc + ((size_t)(b * U_N + u0 + row)) * D_N + col);
        qs[row][col] = v.x; qs[row][col + 1] = v.y; qs[row][col + 2] = v.z; qs[row][col + 3] = v.w;
    }
    __syncthreads();
    int ul = t >> 2, c = t & 3;
    float acc = 0.f;
    for (int d = 0; d < 128; ++d) acc += qs[ul][d] * m3s[d * 4 + c];
    qm[((size_t)(b * U_N + u0 + ul)) * 4 + c] = acc;
}

// ---------- qk MFMA: qkh[b][u][s] = fp16( sum_k qb[b][u][k]*kb[b][s][k] ), bf16 inputs. ----------
__global__ __launch_bounds__(256) void qk_mfma(const unsigned short* __restrict__ qb,
                                               const unsigned short* __restrict__ kb,
                                               _Float16* __restrict__ qkh) {
    const int b = blockIdx.z, u0 = blockIdx.x * 128, s0 = blockIdx.y * 64;
    const int t = threadIdx.x, w = t >> 6, l = t & 63;
    const int lr = l & 15, lq = l >> 4;
    const unsigned short* Ab = qb + ((size_t)(b * U_N + u0 + w * 32 + lr)) * D_N + lq * 8;
    const unsigned short* Bb = kb + ((size_t)(b * S_N + s0 + lr)) * D_N + lq * 8;
    f32x4 acc[2][4] = {};
    #pragma unroll
    for (int kt = 0; kt < 4; ++kt) {
        bf16x8 a0 = *(const bf16x8*)(Ab + kt * 32);
        bf16x8 a1 = *(const bf16x8*)(Ab + 16 * D_N + kt * 32);
        #pragma unroll
        for (int c = 0; c < 4; ++c) {
            bf16x8 bf = *(const bf16x8*)(Bb + c * 16 * D_N + kt * 32);
            acc[0][c] = __builtin_amdgcn_mfma_f32_16x16x32_bf16(a0, bf, acc[0][c], 0, 0, 0);
            acc[1][c] = __builtin_amdgcn_mfma_f32_16x16x32_bf16(a1, bf, acc[1][c], 0, 0, 0);
        }
    }
    __shared__ _Float16 Cs[128][72];
    #pragma unroll
    for (int mt = 0; mt < 2; ++mt)
        #pragma unroll
        for (int c = 0; c < 4; ++c)
            #pragma unroll
            for (int r = 0; r < 4; ++r)
                Cs[w * 32 + mt * 16 + lq * 4 + r][c * 16 + lr] = (_Float16)acc[mt][c][r];
    __syncthreads();
    #pragma unroll
    for (int k = 0; k < 4; ++k) {
        int row = (t >> 3) + k * 32;
        int sg = (t & 7) * 8;
        uint4 v = *(const uint4*)&Cs[row][sg];
        *(uint4*)(qkh + ((size_t)(b * U_N + u0 + row)) * S_N + s0 + sg) = v;
    }
}

// =====================================================================================
// iter_fused(iter): ONE kernel per iteration. 256 blocks x 1024 threads.
//   Phase A (iter>0): redundantly reduce prev-iter partials (launch-boundary coherent,
//   no fences), update this block's 128-user state slice + per-thread server caps.
//   Phase B: score with updated state, write this-iter partials (parity ping-pong).
// Block mapping XCD-pins all 16 blocks of a batch: b=(bid&7)*2|((bid>>3)&1), ublk=bid>>4.
// =====================================================================================
__global__ __launch_bounds__(1024) void iter_fused(
    const _Float16* __restrict__ qkh, const float* __restrict__ qm4,
    const float* __restrict__ nds, const unsigned* __restrict__ connU32,
    const unsigned* __restrict__ fdm_, float* __restrict__ capA,
    const float* __restrict__ invA, const float* __restrict__ usw,
    const float* __restrict__ sbp, const float* __restrict__ fdbp,
    uint4* __restrict__ alloc3, unsigned* __restrict__ rcArr,
    unsigned* __restrict__ seenArr, float* __restrict__ logp,
    ull* __restrict__ keyP, float* __restrict__ sumP,
    unsigned* __restrict__ frozen, int iter) {
    const int bid = blockIdx.x;
    const int b = ((bid & 7) << 1) | ((bid >> 3) & 1);
    const int ublk = bid >> 4;
    if (frozen[b] != 0u) return;        // batch converged in an earlier launch

    __shared__ __align__(16) char smem[56840];
    // phase overlay [0, 49152): score uses mk/me; apply uses ukey/sg/bk/bs/lp
    ull (*mk)[128][4] = (ull (*)[128][4])smem;               // 32768
    float (*me)[128][4] = (float (*)[128][4])(smem + 32768); // 16384
    ull* ukeyL = (ull*)smem;                                 // 16384
    unsigned* sgL = (unsigned*)(smem + 16384);               //  8192
    ull* bkL = (ull*)(smem + 24576);                         //  4096
    float* bsL = (float*)(smem + 28672);                     //  2048
    float* lpL = (float*)(smem + 30720);                     //  2048
    // persistent per-block user state [49152, 56840)
    float4* qmL = (float4*)(smem + 49152);                   // 2048
    float4* ndL = (float4*)(smem + 51200);                   // 2048
    uint4* alL = (uint4*)(smem + 53248);                     // 2048
    unsigned* rcL = (unsigned*)(smem + 55296);               // 512
    unsigned* seenL = (unsigned*)(smem + 55808);             // 512
    float* lpUL = (float*)(smem + 56320);                    // 512
    unsigned* anyL = (unsigned*)(smem + 56832);              // 4

    const int tid = threadIdx.x;
    const int u0 = ublk << 7;
    const int h = tid >> 7;               // user octant (16 users)
    const int sl = tid & 127;             // server quad: 4sl..4sl+3
    const int s0 = sl * 4;
    const float w0 = usw[0], w1 = usw[1], w2 = usw[2], sb = sbp[0], fdb = fdbp[0];
    const float ub0 = sb + w1;
    const float ub1 = sb + w0 * (1.f / 3.f) + w1 * (2.f / 3.f);
    const float ub2 = sb + w0 * (2.f / 3.f) + w1 * (1.f / 3.f) + w2;
    const int bsb = b * S_N + s0;
    const int gub = b * U_N + u0 + h * 16;

    // issue long-latency loads early (used in phase B; hidden under phase A)
    const _Float16* qkbase = qkh + (size_t)gub * S_N + s0;
    f16x4 qv[16];
    #pragma unroll
    for (int uu = 0; uu < 16; ++uu) qv[uu] = *(const f16x4*)(qkbase + (size_t)uu * S_N);
    float4 cap[4], iv[4]; unsigned fq[4];
    #pragma unroll
    for (int j = 0; j < 4; ++j) {
        cap[j] = ((const float4*)capA)[bsb + j];
        iv[j] = ((const float4*)invA)[bsb + j];
        fq[j] = fdm_[bsb + j];
    }
    const int cwbase = gub * 16 + (sl >> 3);
    const int nsh = (sl & 7) * 4;
    ull connbits = 0ULL;
    #pragma unroll
    for (int uu = 0; uu < 16; ++uu)
        connbits |= (ull)((connU32[cwbase + uu * 16] >> nsh) & 0xFu) << (4 * uu);
    if (tid < 128) {
        const int gu = b * U_N + u0 + tid;
        qmL[tid] = ((const float4*)qm4)[gu];
        ndL[tid] = ((const float4*)nds)[gu];
        alL[tid] = alloc3[gu];
        rcL[tid] = rcArr[gu];
        seenL[tid] = seenArr[gu];
        lpUL[tid] = logp[gu];
    }
    __syncthreads();

    if (iter > 0) {
        // ============ phase A: apply prev-iter proposals (redundant per block) ============
        ukeyL[tid] = 0ULL; ukeyL[tid + 1024] = 0ULL;
        sgL[tid] = 0u; sgL[tid + 1024] = 0u;
        if (tid == 0) *anyL = 0u;
        __syncthreads();
        const int s = tid & 511, hh = tid >> 9;
        const size_t pbase = (size_t)((iter - 1) & 1) * (16 * B_N * S_N) + (size_t)b * S_N + s;
        ull best = 0ULL; float ssum = 0.f;
        #pragma unroll
        for (int j = hh * 8; j < hh * 8 + 8; ++j) {
            const ull kk = keyP[pbase + (size_t)j * (B_N * S_N)];
            best = kk > best ? kk : best;
            ssum += sumP[pbase + (size_t)j * (B_N * S_N)];
        }
        if (hh == 0) { bkL[s] = best; bsL[s] = ssum; }
        __syncthreads();
        if (hh == 1) {
            const ull ob = bkL[s];
            best = ob > best ? ob : best;
            ssum += bsL[s];
            bkL[s] = best;                  // final per-server best (for cap updates)
            if (best != 0ULL) {
                const float mx = unmonof((unsigned)(best >> 32));
                const unsigned pu = ~(unsigned)best;   // winning user (ties -> smallest u)
                lpL[s] = mx - __logf(ssum);            // max - logsumexp
                const ull pk = ((ull)monof(mx) << 32) | (~(unsigned)s);
                atomicMax(&ukeyL[pu], pk);
                atomicOr(&sgL[pu], fdm_[b * S_N + s]);
                *anyL = 1u;                  // benign multi-writer of same value
            }
        }
        __syncthreads();
        if (*anyL == 0u) {                  // nothing proposed -> batch frozen forever
            if (tid == 0) frozen[b] = 1u;   // (all 16 blocks agree; redundant same-value writes)
            return;
        }
        // user-state updates: this block's 128-user slice only
        #pragma unroll
        for (int g = 0; g < 2; ++g) {
            const int u = tid + g * 1024;
            if ((u >> 7) == ublk) {
                const ull key = ukeyL[u];
                if (key != 0ULL) {                     // user got >=1 proposal -> accepts
                    const int idx = u & 127;
                    const unsigned s2 = ~(unsigned)key; // accepted server (ties -> smallest s)
                    uint4 al = alL[idx];
                    const unsigned r = rcL[idx];
                    if (r == 0u) al.x = s2; else if (r == 1u) al.y = s2; else al.z = s2;
                    alL[idx] = al;
                    rcL[idx] = r + 1u;
                    seenL[idx] |= sgL[u];
                    lpUL[idx] += lpL[s2];
                }
            }
        }
        // cap updates: per-thread own 4 servers (redundant across blocks, identical result)
        #pragma unroll
        for (int j = 0; j < 4; ++j) {
            const int sj = s0 + j;
            const ull bb = bkL[sj];
            if (bb != 0ULL) {
                const unsigned pu = ~(unsigned)bb;
                if ((~(unsigned)ukeyL[pu]) == (unsigned)sj) {   // server's proposal accepted
                    const float4 nd = ((const float4*)nds)[b * U_N + pu];
                    cap[j].x = fmaxf(cap[j].x - nd.x, 0.f);
                    cap[j].y = fmaxf(cap[j].y - nd.y, 0.f);
                    cap[j].z = fmaxf(cap[j].z - nd.z, 0.f);
                    cap[j].w = fmaxf(cap[j].w - nd.w, 0.f);
                }
            }
        }
        __syncthreads();                    // done with apply overlay
        // write back state (visible to next launch)
        if (tid < 128) {
            const int gu = b * U_N + u0 + tid;
            alloc3[gu] = alL[tid];
            rcArr[gu] = rcL[tid];
            seenArr[gu] = seenL[tid];
            logp[gu] = lpUL[tid];
        }
        if (ublk == 0 && h == 0) {
            #pragma unroll
            for (int j = 0; j < 4; ++j) ((float4*)capA)[bsb + j] = cap[j];
        }
    }

    // ============ phase B: score with updated state ============
    float4 cr[4];
    #pragma unroll
    for (int j = 0; j < 4; ++j)
        cr[j] = make_float4(cap[j].x * iv[j].x, cap[j].y * iv[j].y,
                            cap[j].z * iv[j].z, cap[j].w * iv[j].w);
    ull k[4] = {0ULL, 0ULL, 0ULL, 0ULL};
    float e[4] = {0.f, 0.f, 0.f, 0.f};
    #pragma unroll
    for (int uu = 0; uu < 16; ++uu) {
        const int idx = h * 16 + uu;
        const unsigned rcu = rcL[idx];
        if (rcu < 3u) {                     // saturated users free
            const float4 qmv = qmL[idx];
            const float4 ndv = ndL[idx];
            const unsigned snu = seenL[idx];
            const uint4 al = alL[idx];
            const unsigned nib = (unsigned)(connbits >> (4 * uu)) & 0xFu;
            const float add = (rcu == 0u) ? ub0 : ((rcu == 1u) ? ub1 : ub2);
            const unsigned uinv = ~(unsigned)(u0 + h * 16 + uu);
            #pragma unroll
            for (int j = 0; j < 4; ++j) {
                const unsigned us = (unsigned)(s0 + j);
                const bool ful = (cap[j].x >= ndv.x) & (cap[j].y >= ndv.y) &
                                 (cap[j].z >= ndv.z) & (cap[j].w >= ndv.w);
                const bool aok = (al.x != us) & (al.y != us) & (al.z != us);
                const bool el = (((nib >> j) & 1u) != 0u) & ful & aok;
                const float lg = (float)qv[uu][j] + qmv.x * cr[j].x + qmv.y * cr[j].y +
                                 qmv.z * cr[j].z + qmv.w * cr[j].w + add +
                                 (((snu & fq[j]) == 0u) ? fdb : 0.f);
                if (el) {
                    const ull kk = ((ull)monof(lg) << 32) | uinv;
                    k[j] = k[j] > kk ? k[j] : kk;
                    e[j] += __expf(lg);
                }
            }
        }
    }
    #pragma unroll
    for (int j = 0; j < 4; ++j) { mk[h][sl][j] = k[j]; me[h][sl][j] = e[j]; }
    __syncthreads();
    if (tid < 512) {
        const int sl2 = tid >> 2, j2 = tid & 3;
        ull kb2 = mk[0][sl2][j2];
        float eb = me[0][sl2][j2];
        #pragma unroll
        for (int o = 1; o < 8; ++o) {
            const ull kk = mk[o][sl2][j2];
            kb2 = kk > kb2 ? kk : kb2;
            eb += me[o][sl2][j2];
        }
        const size_t p = (size_t)(iter & 1) * (16 * B_N * S_N) +
                         (size_t)ublk * (B_N * S_N) + (size_t)b * S_N + tid;
        keyP[p] = kb2;
        sumP[p] = eb;
    }
}

// =====================================================================================
// final_apply: apply the last iteration's partials, then emit all outputs.
// =====================================================================================
__global__ __launch_bounds__(1024) void final_apply(
    const float* __restrict__ nds, const unsigned* __restrict__ fdm_,
    const float* __restrict__ capA, const uint4* __restrict__ alloc3,
    const unsigned* __restrict__ rcArr, const float* __restrict__ logp,
    const ull* __restrict__ keyP, const float* __restrict__ sumP,
    const unsigned* __restrict__ frozen, float* __restrict__ out) {
    const int bid = blockIdx.x;
    const int b = ((bid & 7) << 1) | ((bid >> 3) & 1);
    const int ublk = bid >> 4;
    __shared__ __align__(16) char smem[40324];
    ull* ukeyL = (ull*)smem;                                 // 16384
    ull* bkL = (ull*)(smem + 16384);                         //  4096
    float* bsL = (float*)(smem + 20480);                     //  2048
    float* lpL = (float*)(smem + 22528);                     //  2048
    uint4* alL = (uint4*)(smem + 24576);                     //  2048
    unsigned* rcL = (unsigned*)(smem + 26624);               //   512
    float* lpUL = (float*)(smem + 27136);                    //   512
    const int tid = threadIdx.x;
    const int u0 = ublk << 7;
    const int h = tid >> 7;
    const int sl = tid & 127;
    const int s0 = sl * 4;
    const int bsb = b * S_N + s0;
    const bool fz = (frozen[b] != 0u);

    if (tid < 128) {
        const int gu = b * U_N + u0 + tid;
        alL[tid] = alloc3[gu];
        rcL[tid] = rcArr[gu];
        lpUL[tid] = logp[gu];
    }
    float4 cap[4];
    #pragma unroll
    for (int j = 0; j < 4; ++j) cap[j] = ((const float4*)capA)[bsb + j];
    __syncthreads();

    if (!fz) {
        ukeyL[tid] = 0ULL; ukeyL[tid + 1024] = 0ULL;
        __syncthreads();
        const int s = tid & 511, hh = tid >> 9;
        const size_t pbase = (size_t)1 * (16 * B_N * S_N) + (size_t)b * S_N + s;  // iter15 parity
        ull best = 0ULL; float ssum = 0.f;
        #pragma unroll
        for (int j = hh * 8; j < hh * 8 + 8; ++j) {
            const ull kk = keyP[pbase + (size_t)j * (B_N * S_N)];
            best = kk > best ? kk : best;
            ssum += sumP[pbase + (size_t)j * (B_N * S_N)];
        }
        if (hh == 0) { bkL[s] = best; bsL[s] = ssum; }
        __syncthreads();
        if (hh == 1) {
            const ull ob = bkL[s];
            best = ob > best ? ob : best;
            ssum += bsL[s];
            bkL[s] = best;
            if (best != 0ULL) {
                const float mx = unmonof((unsigned)(best >> 32));
                const unsigned pu = ~(unsigned)best;
                lpL[s] = mx - __logf(ssum);
                const ull pk = ((ull)monof(mx) << 32) | (~(unsigned)s);
                atomicMax(&ukeyL[pu], pk);
            }
        }
        __syncthreads();
        #pragma unroll
        for (int g = 0; g < 2; ++g) {
            const int u = tid + g * 1024;
            if ((u >> 7) == ublk) {
                const ull key = ukeyL[u];
                if (key != 0ULL) {
                    const int idx = u & 127;
                    const unsigned s2 = ~(unsigned)key;
                    uint4 al = alL[idx];
                    const unsigned r = rcL[idx];
                    if (r == 0u) al.x = s2; else if (r == 1u) al.y = s2; else al.z = s2;
                    alL[idx] = al;
                    lpUL[idx] += lpL[s2];
                }
            }
        }
        #pragma unroll
        for (int j = 0; j < 4; ++j) {
            const int sj = s0 + j;
            const ull bb = bkL[sj];
            if (bb != 0ULL) {
                const unsigned pu = ~(unsigned)bb;
                if ((~(unsigned)ukeyL[pu]) == (unsigned)sj) {
                    const float4 nd = ((const float4*)nds)[b * U_N + pu];
                    cap[j].x = fmaxf(cap[j].x - nd.x, 0.f);
                    cap[j].y = fmaxf(cap[j].y - nd.y, 0.f);
                    cap[j].z = fmaxf(cap[j].z - nd.z, 0.f);
                    cap[j].w = fmaxf(cap[j].w - nd.w, 0.f);
                }
            }
        }
        __syncthreads();
    }
    // ---- outputs ----
    // alloc one-hot for this block's 128 users
    const size_t orow = 16 + (size_t)(b * U_N + u0) * S_N;
    for (int i2 = tid; i2 < 128 * 128; i2 += 1024) {
        const int row = i2 >> 7;
        const unsigned c4 = (unsigned)((i2 & 127) * 4);
        const uint4 al = alL[row];
        float4 o;
        o.x = (al.x == c4 + 0u || al.y == c4 + 0u || al.z == c4 + 0u) ? 1.f : 0.f;
        o.y = (al.x == c4 + 1u || al.y == c4 + 1u || al.z == c4 + 1u) ? 1.f : 0.f;
        o.z = (al.x == c4 + 2u || al.y == c4 + 2u || al.z == c4 + 2u) ? 1.f : 0.f;
        o.w = (al.x == c4 + 3u || al.y == c4 + 3u || al.z == c4 + 3u) ? 1.f : 0.f;
        *(float4*)(out + orow + (size_t)row * S_N + c4) = o;
    }
    // logp: block-partial sum of its 128 users -> atomicAdd (out[b] zeroed in init_state)
    float sacc = (tid < 128) ? lpUL[tid] : 0.f;
    #pragma unroll
    for (int m = 1; m < 64; m <<= 1) sacc += __shfl_xor(sacc, m, 64);
    __syncthreads();
    if ((tid & 63) == 0) bsL[tid >> 6] = sacc;
    __syncthreads();
    if (tid == 0) {
        float tt = 0.f;
        #pragma unroll
        for (int i2 = 0; i2 < 16; ++i2) tt += bsL[i2];
        atomicAdd(&out[b], tt);
    }
    // caps
    if (ublk == 0 && h == 0) {
        float* cdst = out + 16 + (size_t)B_N * U_N * S_N + (size_t)b * S_N * 4 + (size_t)s0 * 4;
        *(float4*)(cdst + 0) = cap[0];
        *(float4*)(cdst + 4) = cap[1];
        *(float4*)(cdst + 8) = cap[2];
        *(float4*)(cdst + 12) = cap[3];
    }
}

extern "C" void kernel_launch(void* const* d_in, const int* in_sizes, int n_in,
                              void* d_out, int out_size, void* d_ws, size_t ws_size,
                              hipStream_t stream) {
    const float* user_enc = (const float*)d_in[0];
    const float* server_enc = (const float*)d_in[1];
    const float* users = (const float*)d_in[2];
    const float* servers = (const float*)d_in[3];
    const int* connect = (const int*)d_in[4];
    const int* fd_onehot = (const int*)d_in[5];
    const float* state_proj_w = (const float*)d_in[6];
    const float* state_proj_b = (const float*)d_in[7];
    const float* fd_bias = (const float*)d_in[8];
    const float* ptr_q_w = (const float*)d_in[9];
    const float* ptr_k_w = (const float*)d_in[10];
    const float* user_state_w = (const float*)d_in[11];
    const float* score_bias = (const float*)d_in[12];
    float* out = (float*)d_out;

    char* w = (char*)d_ws;
    _Float16* qkh = (_Float16*)(w + 0);                    // 33554432
    unsigned short* qb = (unsigned short*)(w + 33554432);  //  8388608 -> 41943040
    unsigned short* kb = (unsigned short*)(w + 41943040);  //  2097152 -> 44040192
    float* qm = (float*)(w + 44040192);                    //   524288 -> 44564480
    ull* connU = (ull*)(w + 44564480);                     //  2097152 -> 46661632
    float* nds = (float*)(w + 46661632);                   //   524288 -> 47185920
    unsigned* fdm = (unsigned*)(w + 47185920);             //    32768 -> 47218688
    float* capA = (float*)(w + 47218688);                  //   131072 -> 47349760
    float* invA = (float*)(w + 47349760);                  //   131072 -> 47480832
    float* M3 = (float*)(w + 47480832);                    //     2048 -> 47482880
    unsigned* frozen = (unsigned*)(w + 47482880);          //      256 -> 47483136
    uint4* alloc3 = (uint4*)(w + 47483136);                //   524288 -> 48007424
    unsigned* rcArr = (unsigned*)(w + 48007424);           //   131072 -> 48138496
    unsigned* seenArr = (unsigned*)(w + 48138496);         //   131072 -> 48269568
    float* logp = (float*)(w + 48269568);                  //   131072 -> 48400640
    ull* keyP = (ull*)(w + 48400640);                      //  2097152 -> 50497792  [2][16][B*S]
    float* sumP = (float*)(w + 50497792);                  //  1048576 -> 51546368

    init_state<<<128, 256, 0, stream>>>(servers, users, fd_onehot, alloc3, rcArr, seenArr,
                                        logp, capA, invA, fdm, nds, frozen, out);
    pack_connect<<<8192, 256, 0, stream>>>(connect, connU);
    gemm_nt<true, 1><<<dim3(8, 2, 16), 256, 0, stream>>>(server_enc, ptr_k_w, state_proj_b,
                                                         nullptr, kb, S_N, D_N, D_N, INV_SQRT_D);
    gemm_nt<false, 1><<<dim3(32, 2, 16), 256, 0, stream>>>(user_enc, ptr_q_w, nullptr,
                                                           nullptr, qb, U_N, D_N, D_N, 1.0f);
    m3_kernel<<<1, 512, 0, stream>>>(ptr_k_w, state_proj_w, ptr_q_w, M3);
    qm_kernel<<<dim3(32, 16), 256, 0, stream>>>(user_enc, M3, qm);
    qk_mfma<<<dim3(16, 8, 16), 256, 0, stream>>>(qb, kb, qkh);

    for (int it = 0; it < 16; ++it)
        iter_fused<<<256, 1024, 0, stream>>>(qkh, qm, nds, (const unsigned*)connU, fdm,
                                             capA, invA, user_state_w, score_bias, fd_bias,
                                             alloc3, rcArr, seenArr, logp, keyP, sumP,
                                             frozen, it);
    final_apply<<<256, 1024, 0, stream>>>(nds, fdm, capA, alloc3, rcArr, logp,
                                          keyP, sumP, frozen, out);
}